// Round 9
// baseline (477.772 us; speedup 1.0000x reference)
//
#include <hip/hip_runtime.h>

typedef unsigned short u16;
typedef unsigned int   u32;
typedef __attribute__((ext_vector_type(4))) float f32x4;
typedef __attribute__((ext_vector_type(4))) u32   u32x4;
typedef __attribute__((ext_vector_type(8))) __bf16 bf16x8;

#define S_LEN 2048
#define EMB   2048
#define NH    16
#define HD    128
#define NBH   32
#define MTOT  4096
#define NBMIN 512

__device__ __forceinline__ u16 f2bf(float f) {
    u32 u = __float_as_uint(f);
    return (u16)((u + 0x7FFFu + ((u >> 16) & 1u)) >> 16);
}
__device__ __forceinline__ float bf2f(u16 v) {
    return __uint_as_float(((u32)v) << 16);
}
__device__ __forceinline__ bf16x8 ld_frag(const u16* p) {
    return __builtin_bit_cast(bf16x8, *(const u32x4*)p);
}
__device__ __forceinline__ void gld_lds16(const void* g, void* l) {
    __builtin_amdgcn_global_load_lds(
        (__attribute__((address_space(1))) void*)(g),
        (__attribute__((address_space(3))) void*)(l), 16, 0, 0);
}

// ============================================================================
// cast X fp32 -> bf16
// ============================================================================
__global__ __launch_bounds__(256) void cast_x_kernel(
    const float* __restrict__ X, u16* __restrict__ Xb)
{
    const size_t i = ((size_t)blockIdx.x * 256 + threadIdx.x) * 8;
    float4 a = *(const float4*)&X[i];
    float4 b = *(const float4*)&X[i + 4];
    u32x4 o;
    o.x = (u32)f2bf(a.x) | ((u32)f2bf(a.y) << 16);
    o.y = (u32)f2bf(a.z) | ((u32)f2bf(a.w) << 16);
    o.z = (u32)f2bf(b.x) | ((u32)f2bf(b.y) << 16);
    o.w = (u32)f2bf(b.z) | ((u32)f2bf(b.w) << 16);
    *(u32x4*)&Xb[i] = o;
}

// ============================================================================
// transpose-cast weights: W [K][N] fp32 -> Wt [N][K] bf16
// ============================================================================
__global__ __launch_bounds__(256) void transpose_cast_w_kernel(
    const float* __restrict__ W0, const float* __restrict__ W1,
    const float* __restrict__ W2, const float* __restrict__ W3,
    u16* __restrict__ T0, u16* __restrict__ T1,
    u16* __restrict__ T2, u16* __restrict__ T3)
{
    __shared__ float Ls[64][68];
    const int t = threadIdx.x;
    const int n0 = blockIdx.x * 64, k0 = blockIdx.y * 64;
    const int z = blockIdx.z;
    const float* __restrict__ W = (z == 0) ? W0 : (z == 1) ? W1 : (z == 2) ? W2 : W3;
    u16* __restrict__ T = (z == 0) ? T0 : (z == 1) ? T1 : (z == 2) ? T2 : T3;

#pragma unroll
    for (int p = 0; p < 4; ++p) {
        const int r = (t >> 4) + 16 * p;
        const int c = (t & 15) * 4;
        *(float4*)&Ls[r][c] = *(const float4*)&W[(size_t)(k0 + r) * EMB + n0 + c];
    }
    __syncthreads();
    const int nl = t >> 2, q = t & 3;
    u32 pk[8];
#pragma unroll
    for (int j = 0; j < 8; ++j) {
        u16 lo = f2bf(Ls[q * 16 + 2 * j][nl]);
        u16 hi = f2bf(Ls[q * 16 + 2 * j + 1][nl]);
        pk[j] = (u32)lo | ((u32)hi << 16);
    }
    u32x4 o0 = {pk[0], pk[1], pk[2], pk[3]};
    u32x4 o1 = {pk[4], pk[5], pk[6], pk[7]};
    u16* dst = &T[(size_t)(n0 + nl) * EMB + k0 + q * 16];
    *(u32x4*)&dst[0] = o0;
    *(u32x4*)&dst[8] = o1;
}

// ============================================================================
// transpose V bf16 [bh][s][d] -> Vt [bh][d][s]
// ============================================================================
__global__ __launch_bounds__(256) void transpose_v_kernel(
    const u16* __restrict__ V, u16* __restrict__ Vt)
{
    __shared__ u16 Ls[64][72];
    const int t = threadIdx.x;
    const int s0 = blockIdx.x * 64, d0 = blockIdx.y * 64, bh = blockIdx.z;
    const u16* __restrict__ src0 = V + ((size_t)bh * S_LEN) * HD;
    {
        const int r = t >> 2, c0 = (t & 3) * 16;
        const u16* src = &src0[(size_t)(s0 + r) * HD + d0 + c0];
        *(u32x4*)&Ls[r][c0]     = *(const u32x4*)&src[0];
        *(u32x4*)&Ls[r][c0 + 8] = *(const u32x4*)&src[8];
    }
    __syncthreads();
    const int dl = t >> 2, q = t & 3;
    u32 pk[8];
#pragma unroll
    for (int j = 0; j < 8; ++j) {
        u16 lo = Ls[q * 16 + 2 * j][dl];
        u16 hi = Ls[q * 16 + 2 * j + 1][dl];
        pk[j] = (u32)lo | ((u32)hi << 16);
    }
    u32x4 o0 = {pk[0], pk[1], pk[2], pk[3]};
    u32x4 o1 = {pk[4], pk[5], pk[6], pk[7]};
    u16* dst = &Vt[((size_t)bh * HD + d0 + dl) * S_LEN + s0 + q * 16];
    *(u32x4*)&dst[0] = o0;
    *(u32x4*)&dst[8] = o1;
}

// ============================================================================
// gemm_qkv: 256x256 8-phase-style schedule (m201 template, plain HIP).
// 512 threads / 8 waves (2M x 4N), per-wave output 128x64 (acc[8][4]).
// BK=64; LDS = 2 slots x (A 32KB + B 32KB) = 128 KB -> 1 block/CU.
// Per K-tile t (slot t&1): 4 phases, each {stage-issue || ds_read frags ||
// s_barrier || setprio(1) 16 MFMA setprio(0)}; next tile t+1 staged into the
// DEAD slot (it held t-1, consumed before t began) with all 8 issues
// front-loaded into phases 0-1, so the tile-end __syncthreads drain sees
// loads >= 2 phases old. B-frags (both qn halves) held in registers across
// all 4 phases; A-frags swapped at the qm boundary -> 24 ds_read_b128 + 64
// MFMA per tile per wave. Source-side (r&7) XOR swizzle (R4/R6-verified).
// ============================================================================
__global__ __launch_bounds__(512, 2) void gemm_qkv_mfma(
    const u16* __restrict__ Xb,
    const u16* __restrict__ Wtq, const u16* __restrict__ Wtk,
    const u16* __restrict__ Wtv,
    u16* __restrict__ Qo, u16* __restrict__ Ko, u16* __restrict__ Vo)
{
    __shared__ __attribute__((aligned(16))) u16 As[2][256 * 64];
    __shared__ __attribute__((aligned(16))) u16 Bs[2][256 * 64];
    const int tid = threadIdx.x;
    const int w = tid >> 6, lane = tid & 63;
    const int wr = w >> 2, wc = w & 3;          // 2(M) x 4(N) wave grid
    const int n0 = blockIdx.x * 256, m0 = blockIdx.y * 256;
    const int z = blockIdx.z;
    const u16* __restrict__ Wt = (z == 0) ? Wtq : (z == 1) ? Wtk : Wtv;
    u16* __restrict__ O = (z == 0) ? Qo : (z == 1) ? Ko : Vo;

    const int w8 = w * 8, l8 = lane >> 3;
    const int scol = ((lane & 7) ^ l8) * 8;     // pre-swizzled source slot
    const int fm = lane & 15, fk = (lane >> 4) * 8;
    const int key = (fm & 7) * 8;               // read-side XOR (u16 units)
    const int q4 = (lane >> 4) * 4;

    const u16* Ag = &Xb[(size_t)(m0 + w8 + l8) * EMB + scol];
    const u16* Bg = &Wt[(size_t)(n0 + w8 + l8) * EMB + scol];

    // one issue stages 64 rows block-wide (8 rows per wave)
#define SA(d_, t_, p_) gld_lds16(Ag + (size_t)((p_) * 64) * EMB + (t_) * 64, \
                                 &As[d_][((p_) * 64 + w8) * 64])
#define SB(d_, t_, p_) gld_lds16(Bg + (size_t)((p_) * 64) * EMB + (t_) * 64, \
                                 &Bs[d_][((p_) * 64 + w8) * 64])

    f32x4 acc[8][4];
#pragma unroll
    for (int i = 0; i < 8; ++i)
#pragma unroll
        for (int j = 0; j < 4; ++j) acc[i][j] = (f32x4)0.0f;

    // prologue: tile 0 -> slot 0
    SA(0, 0, 0); SA(0, 0, 1); SA(0, 0, 2); SA(0, 0, 3);
    SB(0, 0, 0); SB(0, 0, 1); SB(0, 0, 2); SB(0, 0, 3);
    __syncthreads();

    for (int t = 0; t < 32; ++t) {
        const int s = t & 1, d = s ^ 1;
        const u16* Asl = &As[s][0];
        const u16* Bsl = &Bs[s][0];
        bf16x8 af[4][2], bf[2][2][2];

        // ---- phase 0: stage A(t+1); read A-qm0 + B-qn0; MFMA (qm0,qn0) ----
        if (t < 31) { SA(d, t + 1, 0); SA(d, t + 1, 1); SA(d, t + 1, 2); SA(d, t + 1, 3); }
#pragma unroll
        for (int mi = 0; mi < 4; ++mi)
#pragma unroll
            for (int ks = 0; ks < 2; ++ks)
                af[mi][ks] = ld_frag(&Asl[(wr * 128 + mi * 16 + fm) * 64
                                          + ((ks * 32 + fk) ^ key)]);
#pragma unroll
        for (int ni = 0; ni < 2; ++ni)
#pragma unroll
            for (int ks = 0; ks < 2; ++ks)
                bf[0][ni][ks] = ld_frag(&Bsl[(wc * 64 + ni * 16 + fm) * 64
                                             + ((ks * 32 + fk) ^ key)]);
        __builtin_amdgcn_s_barrier();
        __builtin_amdgcn_s_setprio(1);
#pragma unroll
        for (int mi = 0; mi < 4; ++mi)
#pragma unroll
            for (int ni = 0; ni < 2; ++ni)
#pragma unroll
                for (int ks = 0; ks < 2; ++ks)
                    acc[mi][ni] = __builtin_amdgcn_mfma_f32_16x16x32_bf16(
                        af[mi][ks], bf[0][ni][ks], acc[mi][ni], 0, 0, 0);
        __builtin_amdgcn_s_setprio(0);

        // ---- phase 1: stage B(t+1); read B-qn1; MFMA (qm0,qn1) ----
        if (t < 31) { SB(d, t + 1, 0); SB(d, t + 1, 1); SB(d, t + 1, 2); SB(d, t + 1, 3); }
#pragma unroll
        for (int ni = 0; ni < 2; ++ni)
#pragma unroll
            for (int ks = 0; ks < 2; ++ks)
                bf[1][ni][ks] = ld_frag(&Bsl[(wc * 64 + 32 + ni * 16 + fm) * 64
                                             + ((ks * 32 + fk) ^ key)]);
        __builtin_amdgcn_s_barrier();
        __builtin_amdgcn_s_setprio(1);
#pragma unroll
        for (int mi = 0; mi < 4; ++mi)
#pragma unroll
            for (int ni = 0; ni < 2; ++ni)
#pragma unroll
                for (int ks = 0; ks < 2; ++ks)
                    acc[mi][2 + ni] = __builtin_amdgcn_mfma_f32_16x16x32_bf16(
                        af[mi][ks], bf[1][ni][ks], acc[mi][2 + ni], 0, 0, 0);
        __builtin_amdgcn_s_setprio(0);

        // ---- phase 2: read A-qm1 (overwrite af); MFMA (qm1,qn1) ----
#pragma unroll
        for (int mi = 0; mi < 4; ++mi)
#pragma unroll
            for (int ks = 0; ks < 2; ++ks)
                af[mi][ks] = ld_frag(&Asl[(wr * 128 + 64 + mi * 16 + fm) * 64
                                          + ((ks * 32 + fk) ^ key)]);
        __builtin_amdgcn_s_barrier();
        __builtin_amdgcn_s_setprio(1);
#pragma unroll
        for (int mi = 0; mi < 4; ++mi)
#pragma unroll
            for (int ni = 0; ni < 2; ++ni)
#pragma unroll
                for (int ks = 0; ks < 2; ++ks)
                    acc[4 + mi][2 + ni] = __builtin_amdgcn_mfma_f32_16x16x32_bf16(
                        af[mi][ks], bf[1][ni][ks], acc[4 + mi][2 + ni], 0, 0, 0);
        __builtin_amdgcn_s_setprio(0);

        // ---- phase 3: MFMA (qm1,qn0) ----
        __builtin_amdgcn_s_barrier();
        __builtin_amdgcn_s_setprio(1);
#pragma unroll
        for (int mi = 0; mi < 4; ++mi)
#pragma unroll
            for (int ni = 0; ni < 2; ++ni)
#pragma unroll
                for (int ks = 0; ks < 2; ++ks)
                    acc[4 + mi][ni] = __builtin_amdgcn_mfma_f32_16x16x32_bf16(
                        af[mi][ks], bf[0][ni][ks], acc[4 + mi][ni], 0, 0, 0);
        __builtin_amdgcn_s_setprio(0);

        __syncthreads();  // tile boundary: drains t+1's staging (>=2 phases old)
    }

    // C-write (interleaved [b][h][s][d] output, as before)
#pragma unroll
    for (int mi8 = 0; mi8 < 8; ++mi8)
#pragma unroll
        for (int nj = 0; nj < 4; ++nj) {
            const int n = n0 + wc * 64 + nj * 16 + fm;
            const int h = n >> 7, dd = n & 127;
#pragma unroll
            for (int r = 0; r < 4; ++r) {
                const int m = m0 + wr * 128 + mi8 * 16 + q4 + r;
                const int bb = m >> 11, ss = m & 2047;
                O[(((size_t)(bb * NH + h) * S_LEN) + ss) * HD + dd] =
                    f2bf(acc[mi8][nj][r]);
            }
        }
#undef SA
#undef SB
}

// ============================================================================
// gemm_out: R7-proven 128x128, BK=64 + source-side XOR swizzle.
// ============================================================================
__global__ __launch_bounds__(256) void gemm_out_mfma(
    const u16* __restrict__ Ab, const u16* __restrict__ Wto,
    const float* __restrict__ bias, float* __restrict__ Out)
{
    __shared__ __attribute__((aligned(16))) u16 As[128 * 64];
    __shared__ __attribute__((aligned(16))) u16 Bs[128 * 64];
    const int t = threadIdx.x;
    const int w = t >> 6, lane = t & 63;
    const int wy = w >> 1, wx = w & 1;
    const int n0 = blockIdx.x * 128, m0 = blockIdx.y * 128;

    const int srow8 = lane >> 3;
    const int scol  = ((lane & 7) ^ srow8) * 8;
    const int fm = lane & 15, fk = (lane >> 4) * 8;
    const int key = (fm & 7) * 8;

    const u16* Ag = &Ab[(size_t)(m0 + w * 32 + srow8) * EMB + scol];
    const u16* Bg = &Wto[(size_t)(n0 + w * 32 + srow8) * EMB + scol];
    u16* const Al = &As[(w * 32) * 64];
    u16* const Bl = &Bs[(w * 32) * 64];

    f32x4 acc[4][4];
#pragma unroll
    for (int i = 0; i < 4; ++i)
#pragma unroll
        for (int j = 0; j < 4; ++j) acc[i][j] = (f32x4)0.0f;

    for (int k0 = 0; k0 < EMB; k0 += 64) {
        __syncthreads();
        gld_lds16(Ag + k0,               Al);
        gld_lds16(Ag + k0 + 8 * EMB,     Al + 8 * 64);
        gld_lds16(Ag + k0 + 16 * EMB,    Al + 16 * 64);
        gld_lds16(Ag + k0 + 24 * EMB,    Al + 24 * 64);
        gld_lds16(Bg + k0,               Bl);
        gld_lds16(Bg + k0 + 8 * EMB,     Bl + 8 * 64);
        gld_lds16(Bg + k0 + 16 * EMB,    Bl + 16 * 64);
        gld_lds16(Bg + k0 + 24 * EMB,    Bl + 24 * 64);
        __syncthreads();
#pragma unroll
        for (int dk2 = 0; dk2 < 2; ++dk2) {
            bf16x8 af[4], bfr[4];
#pragma unroll
            for (int mi = 0; mi < 4; ++mi)
                af[mi] = ld_frag(&As[(64 * wy + 16 * mi + fm) * 64
                                     + ((dk2 * 32 + fk) ^ key)]);
#pragma unroll
            for (int ni = 0; ni < 4; ++ni)
                bfr[ni] = ld_frag(&Bs[(64 * wx + 16 * ni + fm) * 64
                                      + ((dk2 * 32 + fk) ^ key)]);
#pragma unroll
            for (int mi = 0; mi < 4; ++mi)
#pragma unroll
                for (int ni = 0; ni < 4; ++ni)
                    acc[mi][ni] = __builtin_amdgcn_mfma_f32_16x16x32_bf16(
                        af[mi], bfr[ni], acc[mi][ni], 0, 0, 0);
        }
    }

    const int q4 = (lane >> 4) * 4;
#pragma unroll
    for (int mi = 0; mi < 4; ++mi)
#pragma unroll
        for (int ni = 0; ni < 4; ++ni) {
            const int n = n0 + 64 * wx + 16 * ni + (lane & 15);
            const float bv = bias[n];
#pragma unroll
            for (int r = 0; r < 4; ++r) {
                const int m = m0 + 64 * wy + 16 * mi + q4 + r;
                Out[(size_t)m * EMB + n] = acc[mi][ni][r] + bv;
            }
        }
}

// ============================================================================
// V suffix sums (bf16 in, bf16 out; fp32 carry)
// ============================================================================
__global__ __launch_bounds__(128) void vchunk_sum_kernel(
    const u16* __restrict__ V, float* __restrict__ csum)
{
    const int chunk = blockIdx.x, bh = blockIdx.y, d = threadIdx.x;
    const u16* vb = V + ((size_t)bh * S_LEN + chunk * 64) * HD + d;
    float s = 0.0f;
    for (int r = 0; r < 64; ++r) s += bf2f(vb[(size_t)r * HD]);
    csum[((size_t)bh * 32 + chunk) * HD + d] = s;
}

// fused: each block derives its own carry (sum of later chunks' csum,
// descending order = original FP order).
__global__ __launch_bounds__(128) void vsuffix_kernel(
    const u16* __restrict__ V, const float* __restrict__ csum,
    u16* __restrict__ vsuf)
{
    const int chunk = blockIdx.x, bh = blockIdx.y, d = threadIdx.x;
    float run = 0.0f;
    for (int c = 31; c > chunk; --c)
        run += csum[((size_t)bh * 32 + c) * HD + d];
    const size_t base = ((size_t)bh * S_LEN + chunk * 64) * HD + d;
    for (int r = 63; r >= 0; --r) {
        vsuf[base + (size_t)r * HD] = f2bf(run);
        run += bf2f(V[base + (size_t)r * HD]);
    }
}

// ============================================================================
// Pipelined flash attention + full-square min, bf16 MFMA.
// R7-proven: 4 waves / 256t, ping-pong chunk width 64, source-side XOR
// swizzle, XCD-locality remap, setprio(1) around MFMA clusters (+5%, m191).
// ============================================================================
__global__ __launch_bounds__(256) void attn_mfma(
    const u16* __restrict__ Q, const u16* __restrict__ K,
    const u16* __restrict__ Vt,
    u16* __restrict__ pacc0, u16* __restrict__ pacc1,
    float* __restrict__ den_p, float* __restrict__ blockmin)
{
    __shared__ __attribute__((aligned(16))) u16 Ps[128 * 136];
    __shared__ __attribute__((aligned(16))) u16 Cs[2][128 * 64];
    __shared__ float den_l[2][128];
    __shared__ float smn[256];

    const int t = threadIdx.x;
    const int w = t >> 6, lane = t & 63;
    const int wy = w >> 1, wx = w & 1;

    // XCD-locality remap (bijective on [0,512)): dispatch id -> logical id.
    const int d_id = blockIdx.y * 16 + blockIdx.x;
    const int f_log = (d_id & 7) * 64 + (d_id >> 3);
    const int pp = (f_log & 15) >> 1, hpar = f_log & 1;
    const int bh = f_log >> 4;
    const int b = bh >> 4, h = bh & 15;

    const u16* __restrict__ Kg  = K + (size_t)bh * S_LEN * HD;
    const u16* __restrict__ Vtg = Vt + (size_t)bh * HD * S_LEN;
    u16* __restrict__ pacc = hpar ? pacc1 : pacc0;

    const int srow8 = lane >> 3;                       // 0..7
    const int scol  = ((lane & 7) ^ srow8) * 8;        // u16 units
    const int fm = lane & 15, fk = (lane >> 4) * 8;
    const int key = (fm & 7) * 8;                      // read-side XOR (u16)
    const int q4 = (lane >> 4) * 4;

#define STAGE_K(b_, j0_, h_) do { \
        const u16* g_ = &Kg[(size_t)((j0_) + w * 32 + srow8) * HD + (h_) * 64 + scol]; \
        u16* l_ = &Cs[b_][(w * 32) * 64]; \
        gld_lds16(g_,           l_); \
        gld_lds16(g_ + 8 * HD,  l_ + 8 * 64); \
        gld_lds16(g_ + 16 * HD, l_ + 16 * 64); \
        gld_lds16(g_ + 24 * HD, l_ + 24 * 64); } while (0)
#define STAGE_V(b_, j0_, h_) do { \
        const u16* g_ = &Vtg[(size_t)(w * 32 + srow8) * S_LEN + (j0_) + (h_) * 64 + scol]; \
        u16* l_ = &Cs[b_][(w * 32) * 64]; \
        gld_lds16(g_,              l_); \
        gld_lds16(g_ + 8 * S_LEN,  l_ + 8 * 64); \
        gld_lds16(g_ + 16 * S_LEN, l_ + 16 * 64); \
        gld_lds16(g_ + 24 * S_LEN, l_ + 24 * 64); } while (0)

    float mn = 3.0e38f;
    int c = 0;

    STAGE_K(0, hpar * 128, 0);
    __syncthreads();

    for (int pass = 0; pass < 2; ++pass) {
        const int qt = pass ? (15 - pp) : pp;
        const int i0 = qt * 128;
        const u16* __restrict__ Qg = Q + ((size_t)bh * S_LEN + i0) * HD;

        bf16x8 af[4][4];
#pragma unroll
        for (int mi = 0; mi < 4; ++mi)
#pragma unroll
            for (int dk = 0; dk < 4; ++dk)
                af[mi][dk] = ld_frag(
                    &Qg[(size_t)(64 * wy + 16 * mi + fm) * HD + dk * 32 + fk]);

        f32x4 oacc[4][4];
#pragma unroll
        for (int i = 0; i < 4; ++i)
#pragma unroll
            for (int j = 0; j < 4; ++j) oacc[i][j] = (f32x4)0.0f;
        float den[4][4] = {};

        for (int ji = 0; ji < 8; ++ji) {
            const int jt = hpar + 2 * ji;
            const int j0 = jt * 128;
            const bool causal = (jt <= qt);
            const bool hn = (ji < 7) || (pass == 0);
            const int nj0 = (ji < 7) ? (jt + 2) * 128 : hpar * 128;

            f32x4 sacc[4][4];
#pragma unroll
            for (int i = 0; i < 4; ++i)
#pragma unroll
                for (int j = 0; j < 4; ++j) sacc[i][j] = (f32x4)0.0f;

            // ---- QK chunk h=0 (d 0..63); prefetch K d-half 1 ----
            STAGE_K(c ^ 1, j0, 1);
#pragma unroll
            for (int dk2 = 0; dk2 < 2; ++dk2) {
                bf16x8 bfr[4];
#pragma unroll
                for (int ni = 0; ni < 4; ++ni)
                    bfr[ni] = ld_frag(&Cs[c][(64 * wx + 16 * ni + fm) * 64
                                             + ((dk2 * 32 + fk) ^ key)]);
                __builtin_amdgcn_s_setprio(1);
#pragma unroll
                for (int mi = 0; mi < 4; ++mi)
#pragma unroll
                    for (int ni = 0; ni < 4; ++ni)
                        sacc[mi][ni] = __builtin_amdgcn_mfma_f32_16x16x32_bf16(
                            af[mi][dk2], bfr[ni], sacc[mi][ni], 0, 0, 0);
                __builtin_amdgcn_s_setprio(0);
            }
            __syncthreads();
            c ^= 1;

            // ---- QK chunk h=1 (d 64..127); prefetch V s-half 0 / next K ----
            if (causal)      STAGE_V(c ^ 1, j0, 0);
            else if (hn)     STAGE_K(c ^ 1, nj0, 0);
#pragma unroll
            for (int dk2 = 0; dk2 < 2; ++dk2) {
                bf16x8 bfr[4];
#pragma unroll
                for (int ni = 0; ni < 4; ++ni)
                    bfr[ni] = ld_frag(&Cs[c][(64 * wx + 16 * ni + fm) * 64
                                             + ((dk2 * 32 + fk) ^ key)]);
                __builtin_amdgcn_s_setprio(1);
#pragma unroll
                for (int mi = 0; mi < 4; ++mi)
#pragma unroll
                    for (int ni = 0; ni < 4; ++ni)
                        sacc[mi][ni] = __builtin_amdgcn_mfma_f32_16x16x32_bf16(
                            af[mi][2 + dk2], bfr[ni], sacc[mi][ni], 0, 0, 0);
                __builtin_amdgcn_s_setprio(0);
            }
            // epilogue overlaps the in-flight DMA
            if (causal) {
                const bool dg = (jt == qt);
#pragma unroll
                for (int mi = 0; mi < 4; ++mi) {
                    const int rbase = 64 * wy + 16 * mi + q4;
#pragma unroll
                    for (int ni = 0; ni < 4; ++ni) {
                        const int cl = 64 * wx + 16 * ni + fm;
                        const int jg = j0 + cl;
#pragma unroll
                        for (int r = 0; r < 4; ++r) {
                            const float s = sacc[mi][ni][r];
                            mn = fminf(mn, s);
                            float e = __expf(s);
                            if (dg && jg > i0 + rbase + r) e = 0.0f;
                            den[mi][r] += e;
                            Ps[(rbase + r) * 136 + cl] = f2bf(e);
                        }
                    }
                }
            } else {
#pragma unroll
                for (int mi = 0; mi < 4; ++mi)
#pragma unroll
                    for (int ni = 0; ni < 4; ++ni)
#pragma unroll
                        for (int r = 0; r < 4; ++r)
                            mn = fminf(mn, sacc[mi][ni][r]);
            }
            __syncthreads();
            c ^= 1;

            // ---- PV: 2 chunks of 64 s-cols (causal only) ----
            if (causal) {
                STAGE_V(c ^ 1, j0, 1);
#pragma unroll
                for (int sk2 = 0; sk2 < 2; ++sk2) {
                    const int sk = sk2;
                    bf16x8 pa[4], pb[4];
#pragma unroll
                    for (int mi = 0; mi < 4; ++mi)
                        pa[mi] = ld_frag(&Ps[(64 * wy + 16 * mi + fm) * 136
                                             + sk * 32 + fk]);
#pragma unroll
                    for (int ni = 0; ni < 4; ++ni)
                        pb[ni] = ld_frag(&Cs[c][(64 * wx + 16 * ni + fm) * 64
                                                + ((sk2 * 32 + fk) ^ key)]);
                    __builtin_amdgcn_s_setprio(1);
#pragma unroll
                    for (int mi = 0; mi < 4; ++mi)
#pragma unroll
                        for (int ni = 0; ni < 4; ++ni)
                            oacc[mi][ni] = __builtin_amdgcn_mfma_f32_16x16x32_bf16(
                                pa[mi], pb[ni], oacc[mi][ni], 0, 0, 0);
                    __builtin_amdgcn_s_setprio(0);
                }
                __syncthreads();
                c ^= 1;

                if (hn) STAGE_K(c ^ 1, nj0, 0);
#pragma unroll
                for (int sk2 = 0; sk2 < 2; ++sk2) {
                    const int sk = 2 + sk2;
                    bf16x8 pa[4], pb[4];
#pragma unroll
                    for (int mi = 0; mi < 4; ++mi)
                        pa[mi] = ld_frag(&Ps[(64 * wy + 16 * mi + fm) * 136
                                             + sk * 32 + fk]);
#pragma unroll
                    for (int ni = 0; ni < 4; ++ni)
                        pb[ni] = ld_frag(&Cs[c][(64 * wx + 16 * ni + fm) * 64
                                                + ((sk2 * 32 + fk) ^ key)]);
                    __builtin_amdgcn_s_setprio(1);
#pragma unroll
                    for (int mi = 0; mi < 4; ++mi)
#pragma unroll
                        for (int ni = 0; ni < 4; ++ni)
                            oacc[mi][ni] = __builtin_amdgcn_mfma_f32_16x16x32_bf16(
                                pa[mi], pb[ni], oacc[mi][ni], 0, 0, 0);
                    __builtin_amdgcn_s_setprio(0);
                }
                __syncthreads();
                c ^= 1;
            }
        }

        // ---- pass epilogue: den reduce + raw partial write ----
#pragma unroll
        for (int mi = 0; mi < 4; ++mi)
#pragma unroll
            for (int r = 0; r < 4; ++r) {
                float v = den[mi][r];
                v += __shfl_xor(v, 1, 64);
                v += __shfl_xor(v, 2, 64);
                v += __shfl_xor(v, 4, 64);
                v += __shfl_xor(v, 8, 64);
                den[mi][r] = v;
            }
        __syncthreads();
        if ((lane & 15) == 0) {
#pragma unroll
            for (int mi = 0; mi < 4; ++mi)
#pragma unroll
                for (int r = 0; r < 4; ++r)
                    den_l[wx][64 * wy + 16 * mi + q4 + r] = den[mi][r];
        }
        __syncthreads();
        if (t < 128)
            den_p[((size_t)hpar * NBH + bh) * S_LEN + i0 + t] =
                den_l[0][t] + den_l[1][t];

#pragma unroll
        for (int mi = 0; mi < 4; ++mi)
#pragma unroll
            for (int ni = 0; ni < 4; ++ni) {
                const int d = 64 * wx + 16 * ni + fm;
#pragma unroll
                for (int r = 0; r < 4; ++r) {
                    const int row = 64 * wy + 16 * mi + q4 + r;
                    pacc[((size_t)b * S_LEN + i0 + row) * EMB + h * HD + d] =
                        f2bf(oacc[mi][ni][r]);
                }
            }
        __syncthreads();  // den_l reuse next pass
    }

    // ---- block min ----
    smn[t] = mn;
    __syncthreads();
    for (int sft = 128; sft > 0; sft >>= 1) {
        if (t < sft) smn[t] = fminf(smn[t], smn[t + sft]);
        __syncthreads();
    }
    if (t == 0) blockmin[d_id] = smn[0];

#undef STAGE_K
#undef STAGE_V
}

// ============================================================================
// finalize: outm = (p0 + p1 + em*vsuf) / (den0 + den1 + (S-1-s)*em), in place.
// Computes the global min from blockmin in-block (deterministic, identical
// reduction order in every block).
// ============================================================================
__global__ __launch_bounds__(256) void finalize_kernel(
    u16* __restrict__ outm, const u16* __restrict__ pacc1,
    const u16* __restrict__ vsuf, const float* __restrict__ den_p,
    const float* __restrict__ blockmin)
{
    __shared__ float wmin[4];
    const int t = threadIdx.x;
    float m = 3.0e38f;
    for (int ii = t; ii < NBMIN; ii += 256)
        m = fminf(m, blockmin[ii]);
    m = fminf(m, __shfl_xor(m, 1, 64));
    m = fminf(m, __shfl_xor(m, 2, 64));
    m = fminf(m, __shfl_xor(m, 4, 64));
    m = fminf(m, __shfl_xor(m, 8, 64));
    m = fminf(m, __shfl_xor(m, 16, 64));
    m = fminf(m, __shfl_xor(m, 32, 64));
    if ((t & 63) == 0) wmin[t >> 6] = m;
    __syncthreads();
    m = fminf(fminf(wmin[0], wmin[1]), fminf(wmin[2], wmin[3]));
    const float em = __expf(m);

    const size_t i = ((size_t)blockIdx.x * 256 + threadIdx.x) * 8;
    const int e = (int)(i & (EMB - 1));
    const int mm = (int)(i / EMB);
    const int b = mm >> 11, s = mm & 2047;
    const int hh = e >> 7, d = e & 127;
    const int bh = b * NH + hh;
    const float den = den_p[(size_t)bh * S_LEN + s]
                    + den_p[((size_t)NBH + bh) * S_LEN + s]
                    + (float)(S_LEN - 1 - s) * em;
    const float inv = 1.0f / den;
    u32x4 a = *(const u32x4*)&outm[i];
    u32x4 cc = *(const u32x4*)&pacc1[i];
    u32x4 vv = *(const u32x4*)&vsuf[((size_t)bh * S_LEN + s) * HD + d];
    const u16* pa = (const u16*)&a;
    const u16* pc = (const u16*)&cc;
    const u16* pv = (const u16*)&vv;
    u16 ov[8];
#pragma unroll
    for (int j = 0; j < 8; ++j) {
        const float v = bf2f(pa[j]) + bf2f(pc[j]) + em * bf2f(pv[j]);
        ov[j] = f2bf(v * inv);
    }
    *(u32x4*)&outm[i] = *(const u32x4*)ov;
}

// ============================================================================
// Launch
// ============================================================================
extern "C" void kernel_launch(void* const* d_in, const int* in_sizes, int n_in,
                              void* d_out, int out_size, void* d_ws, size_t ws_size,
                              hipStream_t stream)
{
    (void)in_sizes; (void)n_in; (void)out_size; (void)ws_size;
    const float* hs = (const float*)d_in[0];
    const float* wq = (const float*)d_in[1];
    const float* wk = (const float*)d_in[2];
    const float* wv = (const float*)d_in[3];
    const float* wo = (const float*)d_in[4];
    const float* bo = (const float*)d_in[5];
    float* out = (float*)d_out;

    char* p = (char*)d_ws;
    const size_t TS = (size_t)NBH * S_LEN * HD;  // 8388608
    u16* Xb   = (u16*)p; p += (size_t)MTOT * EMB * 2;   // dead after gemm_qkv
    u16* Wtq  = (u16*)p; p += (size_t)EMB * EMB * 2;
    u16* Wtk  = (u16*)p; p += (size_t)EMB * EMB * 2;
    u16* Wtv  = (u16*)p; p += (size_t)EMB * EMB * 2;
    u16* Wto  = (u16*)p; p += (size_t)EMB * EMB * 2;
    u16* Qb   = (u16*)p; p += TS * 2;
    u16* Kb   = (u16*)p; p += TS * 2;
    u16* Vb   = (u16*)p; p += TS * 2;
    u16* Vtb  = (u16*)p; p += TS * 2;
    u16* outm = (u16*)p; p += (size_t)MTOT * EMB * 2;   // pacc0, then merged
    u16* vsuf = (u16*)p; p += TS * 2;
    float* csum     = (float*)p; p += (size_t)NBH * 32 * HD * 4;
    float* blockmin = (float*)p; p += 1024 * 4;
    float* den_p    = (float*)p; p += (size_t)2 * NBH * S_LEN * 4;
    u16* pacc1 = Xb;  // overlay: Xb dead once gemm_qkv has run

    cast_x_kernel<<<4096, 256, 0, stream>>>(hs, Xb);
    transpose_cast_w_kernel<<<dim3(32, 32, 4), 256, 0, stream>>>(
        wq, wk, wv, wo, Wtq, Wtk, Wtv, Wto);

    gemm_qkv_mfma<<<dim3(EMB / 256, MTOT / 256, 3), 512, 0, stream>>>(
        Xb, Wtq, Wtk, Wtv, Qb, Kb, Vb);

    transpose_v_kernel<<<dim3(32, 2, NBH), 256, 0, stream>>>(Vb, Vtb);
    vchunk_sum_kernel<<<dim3(32, NBH), 128, 0, stream>>>(Vb, csum);
    vsuffix_kernel<<<dim3(32, NBH), 128, 0, stream>>>(Vb, csum, vsuf);

    attn_mfma<<<dim3(16, NBH), 256, 0, stream>>>(
        Qb, Kb, Vtb, outm, pacc1, den_p, blockmin);

    finalize_kernel<<<(MTOT * EMB / 8) / 256, 256, 0, stream>>>(
        outm, pacc1, vsuf, den_p, blockmin);

    gemm_out_mfma<<<dim3(EMB / 128, MTOT / 128), 256, 0, stream>>>(
        outm, Wto, bo, out);
}

// Round 10
// 429.193 us; speedup vs baseline: 1.1132x; 1.1132x over previous
//
#include <hip/hip_runtime.h>

typedef unsigned short u16;
typedef unsigned int   u32;
typedef __attribute__((ext_vector_type(4))) float f32x4;
typedef __attribute__((ext_vector_type(4))) u32   u32x4;
typedef __attribute__((ext_vector_type(8))) __bf16 bf16x8;

#define S_LEN 2048
#define EMB   2048
#define NH    16
#define HD    128
#define NBH   32
#define MTOT  4096
#define NBMIN 512

__device__ __forceinline__ u16 f2bf(float f) {
    u32 u = __float_as_uint(f);
    return (u16)((u + 0x7FFFu + ((u >> 16) & 1u)) >> 16);
}
__device__ __forceinline__ float bf2f(u16 v) {
    return __uint_as_float(((u32)v) << 16);
}
__device__ __forceinline__ bf16x8 ld_frag(const u16* p) {
    return __builtin_bit_cast(bf16x8, *(const u32x4*)p);
}
__device__ __forceinline__ void gld_lds16(const void* g, void* l) {
    __builtin_amdgcn_global_load_lds(
        (__attribute__((address_space(1))) void*)(g),
        (__attribute__((address_space(3))) void*)(l), 16, 0, 0);
}

// ============================================================================
// cast X fp32 -> bf16
// ============================================================================
__global__ __launch_bounds__(256) void cast_x_kernel(
    const float* __restrict__ X, u16* __restrict__ Xb)
{
    const size_t i = ((size_t)blockIdx.x * 256 + threadIdx.x) * 8;
    float4 a = *(const float4*)&X[i];
    float4 b = *(const float4*)&X[i + 4];
    u32x4 o;
    o.x = (u32)f2bf(a.x) | ((u32)f2bf(a.y) << 16);
    o.y = (u32)f2bf(a.z) | ((u32)f2bf(a.w) << 16);
    o.z = (u32)f2bf(b.x) | ((u32)f2bf(b.y) << 16);
    o.w = (u32)f2bf(b.z) | ((u32)f2bf(b.w) << 16);
    *(u32x4*)&Xb[i] = o;
}

// ============================================================================
// transpose-cast weights: W [K][N] fp32 -> Wt [N][K] bf16
// ============================================================================
__global__ __launch_bounds__(256) void transpose_cast_w_kernel(
    const float* __restrict__ W0, const float* __restrict__ W1,
    const float* __restrict__ W2, const float* __restrict__ W3,
    u16* __restrict__ T0, u16* __restrict__ T1,
    u16* __restrict__ T2, u16* __restrict__ T3)
{
    __shared__ float Ls[64][68];
    const int t = threadIdx.x;
    const int n0 = blockIdx.x * 64, k0 = blockIdx.y * 64;
    const int z = blockIdx.z;
    const float* __restrict__ W = (z == 0) ? W0 : (z == 1) ? W1 : (z == 2) ? W2 : W3;
    u16* __restrict__ T = (z == 0) ? T0 : (z == 1) ? T1 : (z == 2) ? T2 : T3;

#pragma unroll
    for (int p = 0; p < 4; ++p) {
        const int r = (t >> 4) + 16 * p;
        const int c = (t & 15) * 4;
        *(float4*)&Ls[r][c] = *(const float4*)&W[(size_t)(k0 + r) * EMB + n0 + c];
    }
    __syncthreads();
    const int nl = t >> 2, q = t & 3;
    u32 pk[8];
#pragma unroll
    for (int j = 0; j < 8; ++j) {
        u16 lo = f2bf(Ls[q * 16 + 2 * j][nl]);
        u16 hi = f2bf(Ls[q * 16 + 2 * j + 1][nl]);
        pk[j] = (u32)lo | ((u32)hi << 16);
    }
    u32x4 o0 = {pk[0], pk[1], pk[2], pk[3]};
    u32x4 o1 = {pk[4], pk[5], pk[6], pk[7]};
    u16* dst = &T[(size_t)(n0 + nl) * EMB + k0 + q * 16];
    *(u32x4*)&dst[0] = o0;
    *(u32x4*)&dst[8] = o1;
}

// ============================================================================
// transpose V bf16 [bh][s][d] -> Vt [bh][d][s], fused with per-chunk column
// sums (replaces vchunk_sum_kernel): block tiles are exactly 64(s)x64(d) at
// chunk-aligned s, so each thread sums its 16 transposed elements in fp32
// and a 4-lane shfl combine yields csum[bh][chunk][d].
// ============================================================================
__global__ __launch_bounds__(256) void transpose_v_kernel(
    const u16* __restrict__ V, u16* __restrict__ Vt, float* __restrict__ csum)
{
    __shared__ u16 Ls[64][72];
    const int t = threadIdx.x;
    const int s0 = blockIdx.x * 64, d0 = blockIdx.y * 64, bh = blockIdx.z;
    const u16* __restrict__ src0 = V + ((size_t)bh * S_LEN) * HD;
    {
        const int r = t >> 2, c0 = (t & 3) * 16;
        const u16* src = &src0[(size_t)(s0 + r) * HD + d0 + c0];
        *(u32x4*)&Ls[r][c0]     = *(const u32x4*)&src[0];
        *(u32x4*)&Ls[r][c0 + 8] = *(const u32x4*)&src[8];
    }
    __syncthreads();
    const int dl = t >> 2, q = t & 3;
    u32 pk[8];
    float psum = 0.0f;
#pragma unroll
    for (int j = 0; j < 8; ++j) {
        u16 lo = Ls[q * 16 + 2 * j][dl];
        u16 hi = Ls[q * 16 + 2 * j + 1][dl];
        psum += bf2f(lo) + bf2f(hi);
        pk[j] = (u32)lo | ((u32)hi << 16);
    }
    u32x4 o0 = {pk[0], pk[1], pk[2], pk[3]};
    u32x4 o1 = {pk[4], pk[5], pk[6], pk[7]};
    u16* dst = &Vt[((size_t)bh * HD + d0 + dl) * S_LEN + s0 + q * 16];
    *(u32x4*)&dst[0] = o0;
    *(u32x4*)&dst[8] = o1;
    // combine the 4 q-partials (consecutive lanes) -> chunk column sum
    psum += __shfl_xor(psum, 1, 64);
    psum += __shfl_xor(psum, 2, 64);
    if (q == 0)
        csum[((size_t)bh * 32 + blockIdx.x) * HD + d0 + dl] = psum;
}

// ============================================================================
// bf16 MFMA GEMM, BK=64 + source-side XOR swizzle (R4/R6-proven pattern).
// ============================================================================
__global__ __launch_bounds__(256) void gemm_qkv_mfma(
    const u16* __restrict__ Xb,
    const u16* __restrict__ Wtq, const u16* __restrict__ Wtk,
    const u16* __restrict__ Wtv,
    u16* __restrict__ Qo, u16* __restrict__ Ko, u16* __restrict__ Vo)
{
    __shared__ __attribute__((aligned(16))) u16 As[128 * 64];
    __shared__ __attribute__((aligned(16))) u16 Bs[128 * 64];
    const int t = threadIdx.x;
    const int w = t >> 6, lane = t & 63;
    const int wy = w >> 1, wx = w & 1;
    const int n0 = blockIdx.x * 128, m0 = blockIdx.y * 128;
    const int z = blockIdx.z;
    const u16* __restrict__ Wt = (z == 0) ? Wtq : (z == 1) ? Wtk : Wtv;
    u16* __restrict__ O = (z == 0) ? Qo : (z == 1) ? Ko : Vo;

    const int srow8 = lane >> 3;                 // 0..7
    const int scol  = ((lane & 7) ^ srow8) * 8;  // pre-swizzled source slot
    const int fm = lane & 15, fk = (lane >> 4) * 8;
    const int key = (fm & 7) * 8;                // read-side XOR (u16 units)

    const u16* Ag = &Xb[(size_t)(m0 + w * 32 + srow8) * EMB + scol];
    const u16* Bg = &Wt[(size_t)(n0 + w * 32 + srow8) * EMB + scol];
    u16* const Al = &As[(w * 32) * 64];
    u16* const Bl = &Bs[(w * 32) * 64];

    f32x4 acc[4][4];
#pragma unroll
    for (int i = 0; i < 4; ++i)
#pragma unroll
        for (int j = 0; j < 4; ++j) acc[i][j] = (f32x4)0.0f;

    for (int k0 = 0; k0 < EMB; k0 += 64) {
        __syncthreads();
        gld_lds16(Ag + k0,               Al);
        gld_lds16(Ag + k0 + 8 * EMB,     Al + 8 * 64);
        gld_lds16(Ag + k0 + 16 * EMB,    Al + 16 * 64);
        gld_lds16(Ag + k0 + 24 * EMB,    Al + 24 * 64);
        gld_lds16(Bg + k0,               Bl);
        gld_lds16(Bg + k0 + 8 * EMB,     Bl + 8 * 64);
        gld_lds16(Bg + k0 + 16 * EMB,    Bl + 16 * 64);
        gld_lds16(Bg + k0 + 24 * EMB,    Bl + 24 * 64);
        __syncthreads();
#pragma unroll
        for (int dk2 = 0; dk2 < 2; ++dk2) {
            bf16x8 af[4], bfr[4];
#pragma unroll
            for (int mi = 0; mi < 4; ++mi)
                af[mi] = ld_frag(&As[(64 * wy + 16 * mi + fm) * 64
                                     + ((dk2 * 32 + fk) ^ key)]);
#pragma unroll
            for (int ni = 0; ni < 4; ++ni)
                bfr[ni] = ld_frag(&Bs[(64 * wx + 16 * ni + fm) * 64
                                      + ((dk2 * 32 + fk) ^ key)]);
#pragma unroll
            for (int mi = 0; mi < 4; ++mi)
#pragma unroll
                for (int ni = 0; ni < 4; ++ni)
                    acc[mi][ni] = __builtin_amdgcn_mfma_f32_16x16x32_bf16(
                        af[mi], bfr[ni], acc[mi][ni], 0, 0, 0);
        }
    }

    const int q4 = (lane >> 4) * 4;
#pragma unroll
    for (int mi = 0; mi < 4; ++mi)
#pragma unroll
        for (int ni = 0; ni < 4; ++ni) {
            const int n = n0 + 64 * wx + 16 * ni + (lane & 15);
            const int h = n >> 7, d = n & 127;
#pragma unroll
            for (int r = 0; r < 4; ++r) {
                const int m = m0 + 64 * wy + 16 * mi + q4 + r;
                const int bb = m >> 11, s = m & 2047;
                O[(((size_t)(bb * NH + h) * S_LEN) + s) * HD + d] = f2bf(acc[mi][ni][r]);
            }
        }
}

// ============================================================================
// gemm_out: R7-proven 128x128, BK=64 + source-side XOR swizzle.
// ============================================================================
__global__ __launch_bounds__(256) void gemm_out_mfma(
    const u16* __restrict__ Ab, const u16* __restrict__ Wto,
    const float* __restrict__ bias, float* __restrict__ Out)
{
    __shared__ __attribute__((aligned(16))) u16 As[128 * 64];
    __shared__ __attribute__((aligned(16))) u16 Bs[128 * 64];
    const int t = threadIdx.x;
    const int w = t >> 6, lane = t & 63;
    const int wy = w >> 1, wx = w & 1;
    const int n0 = blockIdx.x * 128, m0 = blockIdx.y * 128;

    const int srow8 = lane >> 3;
    const int scol  = ((lane & 7) ^ srow8) * 8;
    const int fm = lane & 15, fk = (lane >> 4) * 8;
    const int key = (fm & 7) * 8;

    const u16* Ag = &Ab[(size_t)(m0 + w * 32 + srow8) * EMB + scol];
    const u16* Bg = &Wto[(size_t)(n0 + w * 32 + srow8) * EMB + scol];
    u16* const Al = &As[(w * 32) * 64];
    u16* const Bl = &Bs[(w * 32) * 64];

    f32x4 acc[4][4];
#pragma unroll
    for (int i = 0; i < 4; ++i)
#pragma unroll
        for (int j = 0; j < 4; ++j) acc[i][j] = (f32x4)0.0f;

    for (int k0 = 0; k0 < EMB; k0 += 64) {
        __syncthreads();
        gld_lds16(Ag + k0,               Al);
        gld_lds16(Ag + k0 + 8 * EMB,     Al + 8 * 64);
        gld_lds16(Ag + k0 + 16 * EMB,    Al + 16 * 64);
        gld_lds16(Ag + k0 + 24 * EMB,    Al + 24 * 64);
        gld_lds16(Bg + k0,               Bl);
        gld_lds16(Bg + k0 + 8 * EMB,     Bl + 8 * 64);
        gld_lds16(Bg + k0 + 16 * EMB,    Bl + 16 * 64);
        gld_lds16(Bg + k0 + 24 * EMB,    Bl + 24 * 64);
        __syncthreads();
#pragma unroll
        for (int dk2 = 0; dk2 < 2; ++dk2) {
            bf16x8 af[4], bfr[4];
#pragma unroll
            for (int mi = 0; mi < 4; ++mi)
                af[mi] = ld_frag(&As[(64 * wy + 16 * mi + fm) * 64
                                     + ((dk2 * 32 + fk) ^ key)]);
#pragma unroll
            for (int ni = 0; ni < 4; ++ni)
                bfr[ni] = ld_frag(&Bs[(64 * wx + 16 * ni + fm) * 64
                                      + ((dk2 * 32 + fk) ^ key)]);
#pragma unroll
            for (int mi = 0; mi < 4; ++mi)
#pragma unroll
                for (int ni = 0; ni < 4; ++ni)
                    acc[mi][ni] = __builtin_amdgcn_mfma_f32_16x16x32_bf16(
                        af[mi], bfr[ni], acc[mi][ni], 0, 0, 0);
        }
    }

    const int q4 = (lane >> 4) * 4;
#pragma unroll
    for (int mi = 0; mi < 4; ++mi)
#pragma unroll
        for (int ni = 0; ni < 4; ++ni) {
            const int n = n0 + 64 * wx + 16 * ni + (lane & 15);
            const float bv = bias[n];
#pragma unroll
            for (int r = 0; r < 4; ++r) {
                const int m = m0 + 64 * wy + 16 * mi + q4 + r;
                Out[(size_t)m * EMB + n] = acc[mi][ni][r] + bv;
            }
        }
}

// ============================================================================
// vsuffix: each block derives its own carry (sum of later chunks' csum,
// descending order = original FP order), then walks its 64 rows.
// ============================================================================
__global__ __launch_bounds__(128) void vsuffix_kernel(
    const u16* __restrict__ V, const float* __restrict__ csum,
    u16* __restrict__ vsuf)
{
    const int chunk = blockIdx.x, bh = blockIdx.y, d = threadIdx.x;
    float run = 0.0f;
    for (int c = 31; c > chunk; --c)
        run += csum[((size_t)bh * 32 + c) * HD + d];
    const size_t base = ((size_t)bh * S_LEN + chunk * 64) * HD + d;
    for (int r = 63; r >= 0; --r) {
        vsuf[base + (size_t)r * HD] = f2bf(run);
        run += bf2f(V[base + (size_t)r * HD]);
    }
}

// ============================================================================
// Pipelined flash attention + full-square min, bf16 MFMA.
// R7-proven: 4 waves / 256t, ping-pong chunk width 64, source-side XOR
// swizzle, XCD-locality remap, setprio(1) around MFMA clusters (+5%, m191).
// ============================================================================
__global__ __launch_bounds__(256) void attn_mfma(
    const u16* __restrict__ Q, const u16* __restrict__ K,
    const u16* __restrict__ Vt,
    u16* __restrict__ pacc0, u16* __restrict__ pacc1,
    float* __restrict__ den_p, float* __restrict__ blockmin)
{
    __shared__ __attribute__((aligned(16))) u16 Ps[128 * 136];
    __shared__ __attribute__((aligned(16))) u16 Cs[2][128 * 64];
    __shared__ float den_l[2][128];
    __shared__ float smn[256];

    const int t = threadIdx.x;
    const int w = t >> 6, lane = t & 63;
    const int wy = w >> 1, wx = w & 1;

    // XCD-locality remap (bijective on [0,512)): dispatch id -> logical id.
    const int d_id = blockIdx.y * 16 + blockIdx.x;
    const int f_log = (d_id & 7) * 64 + (d_id >> 3);
    const int pp = (f_log & 15) >> 1, hpar = f_log & 1;
    const int bh = f_log >> 4;
    const int b = bh >> 4, h = bh & 15;

    const u16* __restrict__ Kg  = K + (size_t)bh * S_LEN * HD;
    const u16* __restrict__ Vtg = Vt + (size_t)bh * HD * S_LEN;
    u16* __restrict__ pacc = hpar ? pacc1 : pacc0;

    const int srow8 = lane >> 3;                       // 0..7
    const int scol  = ((lane & 7) ^ srow8) * 8;        // u16 units
    const int fm = lane & 15, fk = (lane >> 4) * 8;
    const int key = (fm & 7) * 8;                      // read-side XOR (u16)
    const int q4 = (lane >> 4) * 4;

#define STAGE_K(b_, j0_, h_) do { \
        const u16* g_ = &Kg[(size_t)((j0_) + w * 32 + srow8) * HD + (h_) * 64 + scol]; \
        u16* l_ = &Cs[b_][(w * 32) * 64]; \
        gld_lds16(g_,           l_); \
        gld_lds16(g_ + 8 * HD,  l_ + 8 * 64); \
        gld_lds16(g_ + 16 * HD, l_ + 16 * 64); \
        gld_lds16(g_ + 24 * HD, l_ + 24 * 64); } while (0)
#define STAGE_V(b_, j0_, h_) do { \
        const u16* g_ = &Vtg[(size_t)(w * 32 + srow8) * S_LEN + (j0_) + (h_) * 64 + scol]; \
        u16* l_ = &Cs[b_][(w * 32) * 64]; \
        gld_lds16(g_,              l_); \
        gld_lds16(g_ + 8 * S_LEN,  l_ + 8 * 64); \
        gld_lds16(g_ + 16 * S_LEN, l_ + 16 * 64); \
        gld_lds16(g_ + 24 * S_LEN, l_ + 24 * 64); } while (0)

    float mn = 3.0e38f;
    int c = 0;

    STAGE_K(0, hpar * 128, 0);
    __syncthreads();

    for (int pass = 0; pass < 2; ++pass) {
        const int qt = pass ? (15 - pp) : pp;
        const int i0 = qt * 128;
        const u16* __restrict__ Qg = Q + ((size_t)bh * S_LEN + i0) * HD;

        bf16x8 af[4][4];
#pragma unroll
        for (int mi = 0; mi < 4; ++mi)
#pragma unroll
            for (int dk = 0; dk < 4; ++dk)
                af[mi][dk] = ld_frag(
                    &Qg[(size_t)(64 * wy + 16 * mi + fm) * HD + dk * 32 + fk]);

        f32x4 oacc[4][4];
#pragma unroll
        for (int i = 0; i < 4; ++i)
#pragma unroll
            for (int j = 0; j < 4; ++j) oacc[i][j] = (f32x4)0.0f;
        float den[4][4] = {};

        for (int ji = 0; ji < 8; ++ji) {
            const int jt = hpar + 2 * ji;
            const int j0 = jt * 128;
            const bool causal = (jt <= qt);
            const bool hn = (ji < 7) || (pass == 0);
            const int nj0 = (ji < 7) ? (jt + 2) * 128 : hpar * 128;

            f32x4 sacc[4][4];
#pragma unroll
            for (int i = 0; i < 4; ++i)
#pragma unroll
                for (int j = 0; j < 4; ++j) sacc[i][j] = (f32x4)0.0f;

            // ---- QK chunk h=0 (d 0..63); prefetch K d-half 1 ----
            STAGE_K(c ^ 1, j0, 1);
#pragma unroll
            for (int dk2 = 0; dk2 < 2; ++dk2) {
                bf16x8 bfr[4];
#pragma unroll
                for (int ni = 0; ni < 4; ++ni)
                    bfr[ni] = ld_frag(&Cs[c][(64 * wx + 16 * ni + fm) * 64
                                             + ((dk2 * 32 + fk) ^ key)]);
                __builtin_amdgcn_s_setprio(1);
#pragma unroll
                for (int mi = 0; mi < 4; ++mi)
#pragma unroll
                    for (int ni = 0; ni < 4; ++ni)
                        sacc[mi][ni] = __builtin_amdgcn_mfma_f32_16x16x32_bf16(
                            af[mi][dk2], bfr[ni], sacc[mi][ni], 0, 0, 0);
                __builtin_amdgcn_s_setprio(0);
            }
            __syncthreads();
            c ^= 1;

            // ---- QK chunk h=1 (d 64..127); prefetch V s-half 0 / next K ----
            if (causal)      STAGE_V(c ^ 1, j0, 0);
            else if (hn)     STAGE_K(c ^ 1, nj0, 0);
#pragma unroll
            for (int dk2 = 0; dk2 < 2; ++dk2) {
                bf16x8 bfr[4];
#pragma unroll
                for (int ni = 0; ni < 4; ++ni)
                    bfr[ni] = ld_frag(&Cs[c][(64 * wx + 16 * ni + fm) * 64
                                             + ((dk2 * 32 + fk) ^ key)]);
                __builtin_amdgcn_s_setprio(1);
#pragma unroll
                for (int mi = 0; mi < 4; ++mi)
#pragma unroll
                    for (int ni = 0; ni < 4; ++ni)
                        sacc[mi][ni] = __builtin_amdgcn_mfma_f32_16x16x32_bf16(
                            af[mi][2 + dk2], bfr[ni], sacc[mi][ni], 0, 0, 0);
                __builtin_amdgcn_s_setprio(0);
            }
            // epilogue overlaps the in-flight DMA
            if (causal) {
                const bool dg = (jt == qt);
#pragma unroll
                for (int mi = 0; mi < 4; ++mi) {
                    const int rbase = 64 * wy + 16 * mi + q4;
#pragma unroll
                    for (int ni = 0; ni < 4; ++ni) {
                        const int cl = 64 * wx + 16 * ni + fm;
                        const int jg = j0 + cl;
#pragma unroll
                        for (int r = 0; r < 4; ++r) {
                            const float s = sacc[mi][ni][r];
                            mn = fminf(mn, s);
                            float e = __expf(s);
                            if (dg && jg > i0 + rbase + r) e = 0.0f;
                            den[mi][r] += e;
                            Ps[(rbase + r) * 136 + cl] = f2bf(e);
                        }
                    }
                }
            } else {
#pragma unroll
                for (int mi = 0; mi < 4; ++mi)
#pragma unroll
                    for (int ni = 0; ni < 4; ++ni)
#pragma unroll
                        for (int r = 0; r < 4; ++r)
                            mn = fminf(mn, sacc[mi][ni][r]);
            }
            __syncthreads();
            c ^= 1;

            // ---- PV: 2 chunks of 64 s-cols (causal only) ----
            if (causal) {
                STAGE_V(c ^ 1, j0, 1);
#pragma unroll
                for (int sk2 = 0; sk2 < 2; ++sk2) {
                    const int sk = sk2;
                    bf16x8 pa[4], pb[4];
#pragma unroll
                    for (int mi = 0; mi < 4; ++mi)
                        pa[mi] = ld_frag(&Ps[(64 * wy + 16 * mi + fm) * 136
                                             + sk * 32 + fk]);
#pragma unroll
                    for (int ni = 0; ni < 4; ++ni)
                        pb[ni] = ld_frag(&Cs[c][(64 * wx + 16 * ni + fm) * 64
                                                + ((sk2 * 32 + fk) ^ key)]);
                    __builtin_amdgcn_s_setprio(1);
#pragma unroll
                    for (int mi = 0; mi < 4; ++mi)
#pragma unroll
                        for (int ni = 0; ni < 4; ++ni)
                            oacc[mi][ni] = __builtin_amdgcn_mfma_f32_16x16x32_bf16(
                                pa[mi], pb[ni], oacc[mi][ni], 0, 0, 0);
                    __builtin_amdgcn_s_setprio(0);
                }
                __syncthreads();
                c ^= 1;

                if (hn) STAGE_K(c ^ 1, nj0, 0);
#pragma unroll
                for (int sk2 = 0; sk2 < 2; ++sk2) {
                    const int sk = 2 + sk2;
                    bf16x8 pa[4], pb[4];
#pragma unroll
                    for (int mi = 0; mi < 4; ++mi)
                        pa[mi] = ld_frag(&Ps[(64 * wy + 16 * mi + fm) * 136
                                             + sk * 32 + fk]);
#pragma unroll
                    for (int ni = 0; ni < 4; ++ni)
                        pb[ni] = ld_frag(&Cs[c][(64 * wx + 16 * ni + fm) * 64
                                                + ((sk2 * 32 + fk) ^ key)]);
                    __builtin_amdgcn_s_setprio(1);
#pragma unroll
                    for (int mi = 0; mi < 4; ++mi)
#pragma unroll
                        for (int ni = 0; ni < 4; ++ni)
                            oacc[mi][ni] = __builtin_amdgcn_mfma_f32_16x16x32_bf16(
                                pa[mi], pb[ni], oacc[mi][ni], 0, 0, 0);
                    __builtin_amdgcn_s_setprio(0);
                }
                __syncthreads();
                c ^= 1;
            }
        }

        // ---- pass epilogue: den reduce + raw partial write ----
#pragma unroll
        for (int mi = 0; mi < 4; ++mi)
#pragma unroll
            for (int r = 0; r < 4; ++r) {
                float v = den[mi][r];
                v += __shfl_xor(v, 1, 64);
                v += __shfl_xor(v, 2, 64);
                v += __shfl_xor(v, 4, 64);
                v += __shfl_xor(v, 8, 64);
                den[mi][r] = v;
            }
        __syncthreads();
        if ((lane & 15) == 0) {
#pragma unroll
            for (int mi = 0; mi < 4; ++mi)
#pragma unroll
                for (int r = 0; r < 4; ++r)
                    den_l[wx][64 * wy + 16 * mi + q4 + r] = den[mi][r];
        }
        __syncthreads();
        if (t < 128)
            den_p[((size_t)hpar * NBH + bh) * S_LEN + i0 + t] =
                den_l[0][t] + den_l[1][t];

#pragma unroll
        for (int mi = 0; mi < 4; ++mi)
#pragma unroll
            for (int ni = 0; ni < 4; ++ni) {
                const int d = 64 * wx + 16 * ni + fm;
#pragma unroll
                for (int r = 0; r < 4; ++r) {
                    const int row = 64 * wy + 16 * mi + q4 + r;
                    pacc[((size_t)b * S_LEN + i0 + row) * EMB + h * HD + d] =
                        f2bf(oacc[mi][ni][r]);
                }
            }
        __syncthreads();  // den_l reuse next pass
    }

    // ---- block min ----
    smn[t] = mn;
    __syncthreads();
    for (int sft = 128; sft > 0; sft >>= 1) {
        if (t < sft) smn[t] = fminf(smn[t], smn[t + sft]);
        __syncthreads();
    }
    if (t == 0) blockmin[d_id] = smn[0];

#undef STAGE_K
#undef STAGE_V
}

// ============================================================================
// finalize: outm = (p0 + p1 + em*vsuf) / (den0 + den1 + (S-1-s)*em), in place.
// Computes the global min from blockmin in-block (deterministic, identical
// reduction order in every block).
// ============================================================================
__global__ __launch_bounds__(256) void finalize_kernel(
    u16* __restrict__ outm, const u16* __restrict__ pacc1,
    const u16* __restrict__ vsuf, const float* __restrict__ den_p,
    const float* __restrict__ blockmin)
{
    __shared__ float wmin[4];
    const int t = threadIdx.x;
    float m = 3.0e38f;
    for (int ii = t; ii < NBMIN; ii += 256)
        m = fminf(m, blockmin[ii]);
    m = fminf(m, __shfl_xor(m, 1, 64));
    m = fminf(m, __shfl_xor(m, 2, 64));
    m = fminf(m, __shfl_xor(m, 4, 64));
    m = fminf(m, __shfl_xor(m, 8, 64));
    m = fminf(m, __shfl_xor(m, 16, 64));
    m = fminf(m, __shfl_xor(m, 32, 64));
    if ((t & 63) == 0) wmin[t >> 6] = m;
    __syncthreads();
    m = fminf(fminf(wmin[0], wmin[1]), fminf(wmin[2], wmin[3]));
    const float em = __expf(m);

    const size_t i = ((size_t)blockIdx.x * 256 + threadIdx.x) * 8;
    const int e = (int)(i & (EMB - 1));
    const int mm = (int)(i / EMB);
    const int b = mm >> 11, s = mm & 2047;
    const int hh = e >> 7, d = e & 127;
    const int bh = b * NH + hh;
    const float den = den_p[(size_t)bh * S_LEN + s]
                    + den_p[((size_t)NBH + bh) * S_LEN + s]
                    + (float)(S_LEN - 1 - s) * em;
    const float inv = 1.0f / den;
    u32x4 a = *(const u32x4*)&outm[i];
    u32x4 cc = *(const u32x4*)&pacc1[i];
    u32x4 vv = *(const u32x4*)&vsuf[((size_t)bh * S_LEN + s) * HD + d];
    const u16* pa = (const u16*)&a;
    const u16* pc = (const u16*)&cc;
    const u16* pv = (const u16*)&vv;
    u16 ov[8];
#pragma unroll
    for (int j = 0; j < 8; ++j) {
        const float v = bf2f(pa[j]) + bf2f(pc[j]) + em * bf2f(pv[j]);
        ov[j] = f2bf(v * inv);
    }
    *(u32x4*)&outm[i] = *(const u32x4*)ov;
}

// ============================================================================
// Launch
// ============================================================================
extern "C" void kernel_launch(void* const* d_in, const int* in_sizes, int n_in,
                              void* d_out, int out_size, void* d_ws, size_t ws_size,
                              hipStream_t stream)
{
    (void)in_sizes; (void)n_in; (void)out_size; (void)ws_size;
    const float* hs = (const float*)d_in[0];
    const float* wq = (const float*)d_in[1];
    const float* wk = (const float*)d_in[2];
    const float* wv = (const float*)d_in[3];
    const float* wo = (const float*)d_in[4];
    const float* bo = (const float*)d_in[5];
    float* out = (float*)d_out;

    char* p = (char*)d_ws;
    const size_t TS = (size_t)NBH * S_LEN * HD;  // 8388608
    u16* Xb   = (u16*)p; p += (size_t)MTOT * EMB * 2;   // dead after gemm_qkv
    u16* Wtq  = (u16*)p; p += (size_t)EMB * EMB * 2;
    u16* Wtk  = (u16*)p; p += (size_t)EMB * EMB * 2;
    u16* Wtv  = (u16*)p; p += (size_t)EMB * EMB * 2;
    u16* Wto  = (u16*)p; p += (size_t)EMB * EMB * 2;
    u16* Qb   = (u16*)p; p += TS * 2;
    u16* Kb   = (u16*)p; p += TS * 2;
    u16* Vb   = (u16*)p; p += TS * 2;
    u16* Vtb  = (u16*)p; p += TS * 2;
    u16* outm = (u16*)p; p += (size_t)MTOT * EMB * 2;   // pacc0, then merged
    u16* vsuf = (u16*)p; p += TS * 2;
    float* csum     = (float*)p; p += (size_t)NBH * 32 * HD * 4;
    float* blockmin = (float*)p; p += 1024 * 4;
    float* den_p    = (float*)p; p += (size_t)2 * NBH * S_LEN * 4;
    u16* pacc1 = Xb;  // overlay: Xb dead once gemm_qkv has run

    cast_x_kernel<<<4096, 256, 0, stream>>>(hs, Xb);
    transpose_cast_w_kernel<<<dim3(32, 32, 4), 256, 0, stream>>>(
        wq, wk, wv, wo, Wtq, Wtk, Wtv, Wto);

    gemm_qkv_mfma<<<dim3(EMB / 128, MTOT / 128, 3), 256, 0, stream>>>(
        Xb, Wtq, Wtk, Wtv, Qb, Kb, Vb);

    transpose_v_kernel<<<dim3(32, 2, NBH), 256, 0, stream>>>(Vb, Vtb, csum);
    vsuffix_kernel<<<dim3(32, NBH), 128, 0, stream>>>(Vb, csum, vsuf);

    attn_mfma<<<dim3(16, NBH), 256, 0, stream>>>(
        Qb, Kb, Vtb, outm, pacc1, den_p, blockmin);

    finalize_kernel<<<(MTOT * EMB / 8) / 256, 256, 0, stream>>>(
        outm, pacc1, vsuf, den_p, blockmin);

    gemm_out_mfma<<<dim3(EMB / 128, MTOT / 128), 256, 0, stream>>>(
        outm, Wto, bo, out);
}

// Round 11
// 415.472 us; speedup vs baseline: 1.1500x; 1.0330x over previous
//
#include <hip/hip_runtime.h>

typedef unsigned short u16;
typedef unsigned int   u32;
typedef __attribute__((ext_vector_type(4))) float f32x4;
typedef __attribute__((ext_vector_type(4))) u32   u32x4;
typedef __attribute__((ext_vector_type(8))) __bf16 bf16x8;

#define S_LEN 2048
#define EMB   2048
#define NH    16
#define HD    128
#define NBH   32
#define MTOT  4096
#define NBMIN 512

__device__ __forceinline__ u16 f2bf(float f) {
    u32 u = __float_as_uint(f);
    return (u16)((u + 0x7FFFu + ((u >> 16) & 1u)) >> 16);
}
__device__ __forceinline__ float bf2f(u16 v) {
    return __uint_as_float(((u32)v) << 16);
}
__device__ __forceinline__ bf16x8 ld_frag(const u16* p) {
    return __builtin_bit_cast(bf16x8, *(const u32x4*)p);
}
__device__ __forceinline__ void gld_lds16(const void* g, void* l) {
    __builtin_amdgcn_global_load_lds(
        (__attribute__((address_space(1))) void*)(g),
        (__attribute__((address_space(3))) void*)(l), 16, 0, 0);
}

// ============================================================================
// fused prep: z<4 -> transpose-cast weight W_z [K][N] fp32 -> Wt [N][K] bf16;
// z>=4 -> flat cast of X fp32 -> bf16 (flat block id (z-4)*1024 + y*32 + x).
// Branch is block-uniform (z), so no divergent __syncthreads.
// ============================================================================
__global__ __launch_bounds__(256) void prep_kernel(
    const float* __restrict__ X, u16* __restrict__ Xb,
    const float* __restrict__ W0, const float* __restrict__ W1,
    const float* __restrict__ W2, const float* __restrict__ W3,
    u16* __restrict__ T0, u16* __restrict__ T1,
    u16* __restrict__ T2, u16* __restrict__ T3)
{
    __shared__ float Ls[64][68];
    const int t = threadIdx.x;
    const int z = blockIdx.z;

    if (z >= 4) {
        const int bid = (z - 4) * 1024 + blockIdx.y * 32 + blockIdx.x;
        const size_t i = ((size_t)bid * 256 + t) * 8;
        float4 a = *(const float4*)&X[i];
        float4 b = *(const float4*)&X[i + 4];
        u32x4 o;
        o.x = (u32)f2bf(a.x) | ((u32)f2bf(a.y) << 16);
        o.y = (u32)f2bf(a.z) | ((u32)f2bf(a.w) << 16);
        o.z = (u32)f2bf(b.x) | ((u32)f2bf(b.y) << 16);
        o.w = (u32)f2bf(b.z) | ((u32)f2bf(b.w) << 16);
        *(u32x4*)&Xb[i] = o;
        return;
    }

    const int n0 = blockIdx.x * 64, k0 = blockIdx.y * 64;
    const float* __restrict__ W = (z == 0) ? W0 : (z == 1) ? W1 : (z == 2) ? W2 : W3;
    u16* __restrict__ T = (z == 0) ? T0 : (z == 1) ? T1 : (z == 2) ? T2 : T3;

#pragma unroll
    for (int p = 0; p < 4; ++p) {
        const int r = (t >> 4) + 16 * p;
        const int c = (t & 15) * 4;
        *(float4*)&Ls[r][c] = *(const float4*)&W[(size_t)(k0 + r) * EMB + n0 + c];
    }
    __syncthreads();
    const int nl = t >> 2, q = t & 3;
    u32 pk[8];
#pragma unroll
    for (int j = 0; j < 8; ++j) {
        u16 lo = f2bf(Ls[q * 16 + 2 * j][nl]);
        u16 hi = f2bf(Ls[q * 16 + 2 * j + 1][nl]);
        pk[j] = (u32)lo | ((u32)hi << 16);
    }
    u32x4 o0 = {pk[0], pk[1], pk[2], pk[3]};
    u32x4 o1 = {pk[4], pk[5], pk[6], pk[7]};
    u16* dst = &T[(size_t)(n0 + nl) * EMB + k0 + q * 16];
    *(u32x4*)&dst[0] = o0;
    *(u32x4*)&dst[8] = o1;
}

// ============================================================================
// transpose V bf16 [bh][s][d] -> Vt [bh][d][s], fused with per-chunk column
// sums (csum[bh][chunk][d]); tiles are exactly 64(s)x64(d) chunk-aligned.
// ============================================================================
__global__ __launch_bounds__(256) void transpose_v_kernel(
    const u16* __restrict__ V, u16* __restrict__ Vt, float* __restrict__ csum)
{
    __shared__ u16 Ls[64][72];
    const int t = threadIdx.x;
    const int s0 = blockIdx.x * 64, d0 = blockIdx.y * 64, bh = blockIdx.z;
    const u16* __restrict__ src0 = V + ((size_t)bh * S_LEN) * HD;
    {
        const int r = t >> 2, c0 = (t & 3) * 16;
        const u16* src = &src0[(size_t)(s0 + r) * HD + d0 + c0];
        *(u32x4*)&Ls[r][c0]     = *(const u32x4*)&src[0];
        *(u32x4*)&Ls[r][c0 + 8] = *(const u32x4*)&src[8];
    }
    __syncthreads();
    const int dl = t >> 2, q = t & 3;
    u32 pk[8];
    float psum = 0.0f;
#pragma unroll
    for (int j = 0; j < 8; ++j) {
        u16 lo = Ls[q * 16 + 2 * j][dl];
        u16 hi = Ls[q * 16 + 2 * j + 1][dl];
        psum += bf2f(lo) + bf2f(hi);
        pk[j] = (u32)lo | ((u32)hi << 16);
    }
    u32x4 o0 = {pk[0], pk[1], pk[2], pk[3]};
    u32x4 o1 = {pk[4], pk[5], pk[6], pk[7]};
    u16* dst = &Vt[((size_t)bh * HD + d0 + dl) * S_LEN + s0 + q * 16];
    *(u32x4*)&dst[0] = o0;
    *(u32x4*)&dst[8] = o1;
    psum += __shfl_xor(psum, 1, 64);
    psum += __shfl_xor(psum, 2, 64);
    if (q == 0)
        csum[((size_t)bh * 32 + blockIdx.x) * HD + d0 + dl] = psum;
}

// ============================================================================
// bf16 MFMA GEMM, BK=64 + source-side XOR swizzle (R4/R6-proven pattern).
// ============================================================================
__global__ __launch_bounds__(256) void gemm_qkv_mfma(
    const u16* __restrict__ Xb,
    const u16* __restrict__ Wtq, const u16* __restrict__ Wtk,
    const u16* __restrict__ Wtv,
    u16* __restrict__ Qo, u16* __restrict__ Ko, u16* __restrict__ Vo)
{
    __shared__ __attribute__((aligned(16))) u16 As[128 * 64];
    __shared__ __attribute__((aligned(16))) u16 Bs[128 * 64];
    const int t = threadIdx.x;
    const int w = t >> 6, lane = t & 63;
    const int wy = w >> 1, wx = w & 1;
    const int n0 = blockIdx.x * 128, m0 = blockIdx.y * 128;
    const int z = blockIdx.z;
    const u16* __restrict__ Wt = (z == 0) ? Wtq : (z == 1) ? Wtk : Wtv;
    u16* __restrict__ O = (z == 0) ? Qo : (z == 1) ? Ko : Vo;

    const int srow8 = lane >> 3;                 // 0..7
    const int scol  = ((lane & 7) ^ srow8) * 8;  // pre-swizzled source slot
    const int fm = lane & 15, fk = (lane >> 4) * 8;
    const int key = (fm & 7) * 8;                // read-side XOR (u16 units)

    const u16* Ag = &Xb[(size_t)(m0 + w * 32 + srow8) * EMB + scol];
    const u16* Bg = &Wt[(size_t)(n0 + w * 32 + srow8) * EMB + scol];
    u16* const Al = &As[(w * 32) * 64];
    u16* const Bl = &Bs[(w * 32) * 64];

    f32x4 acc[4][4];
#pragma unroll
    for (int i = 0; i < 4; ++i)
#pragma unroll
        for (int j = 0; j < 4; ++j) acc[i][j] = (f32x4)0.0f;

    for (int k0 = 0; k0 < EMB; k0 += 64) {
        __syncthreads();
        gld_lds16(Ag + k0,               Al);
        gld_lds16(Ag + k0 + 8 * EMB,     Al + 8 * 64);
        gld_lds16(Ag + k0 + 16 * EMB,    Al + 16 * 64);
        gld_lds16(Ag + k0 + 24 * EMB,    Al + 24 * 64);
        gld_lds16(Bg + k0,               Bl);
        gld_lds16(Bg + k0 + 8 * EMB,     Bl + 8 * 64);
        gld_lds16(Bg + k0 + 16 * EMB,    Bl + 16 * 64);
        gld_lds16(Bg + k0 + 24 * EMB,    Bl + 24 * 64);
        __syncthreads();
#pragma unroll
        for (int dk2 = 0; dk2 < 2; ++dk2) {
            bf16x8 af[4], bfr[4];
#pragma unroll
            for (int mi = 0; mi < 4; ++mi)
                af[mi] = ld_frag(&As[(64 * wy + 16 * mi + fm) * 64
                                     + ((dk2 * 32 + fk) ^ key)]);
#pragma unroll
            for (int ni = 0; ni < 4; ++ni)
                bfr[ni] = ld_frag(&Bs[(64 * wx + 16 * ni + fm) * 64
                                      + ((dk2 * 32 + fk) ^ key)]);
#pragma unroll
            for (int mi = 0; mi < 4; ++mi)
#pragma unroll
                for (int ni = 0; ni < 4; ++ni)
                    acc[mi][ni] = __builtin_amdgcn_mfma_f32_16x16x32_bf16(
                        af[mi], bfr[ni], acc[mi][ni], 0, 0, 0);
        }
    }

    const int q4 = (lane >> 4) * 4;
#pragma unroll
    for (int mi = 0; mi < 4; ++mi)
#pragma unroll
        for (int ni = 0; ni < 4; ++ni) {
            const int n = n0 + 64 * wx + 16 * ni + (lane & 15);
            const int h = n >> 7, d = n & 127;
#pragma unroll
            for (int r = 0; r < 4; ++r) {
                const int m = m0 + 64 * wy + 16 * mi + q4 + r;
                const int bb = m >> 11, s = m & 2047;
                O[(((size_t)(bb * NH + h) * S_LEN) + s) * HD + d] = f2bf(acc[mi][ni][r]);
            }
        }
}

// ============================================================================
// gemm_out: R7-proven 128x128, BK=64 + source-side XOR swizzle.
// ============================================================================
__global__ __launch_bounds__(256) void gemm_out_mfma(
    const u16* __restrict__ Ab, const u16* __restrict__ Wto,
    const float* __restrict__ bias, float* __restrict__ Out)
{
    __shared__ __attribute__((aligned(16))) u16 As[128 * 64];
    __shared__ __attribute__((aligned(16))) u16 Bs[128 * 64];
    const int t = threadIdx.x;
    const int w = t >> 6, lane = t & 63;
    const int wy = w >> 1, wx = w & 1;
    const int n0 = blockIdx.x * 128, m0 = blockIdx.y * 128;

    const int srow8 = lane >> 3;
    const int scol  = ((lane & 7) ^ srow8) * 8;
    const int fm = lane & 15, fk = (lane >> 4) * 8;
    const int key = (fm & 7) * 8;

    const u16* Ag = &Ab[(size_t)(m0 + w * 32 + srow8) * EMB + scol];
    const u16* Bg = &Wto[(size_t)(n0 + w * 32 + srow8) * EMB + scol];
    u16* const Al = &As[(w * 32) * 64];
    u16* const Bl = &Bs[(w * 32) * 64];

    f32x4 acc[4][4];
#pragma unroll
    for (int i = 0; i < 4; ++i)
#pragma unroll
        for (int j = 0; j < 4; ++j) acc[i][j] = (f32x4)0.0f;

    for (int k0 = 0; k0 < EMB; k0 += 64) {
        __syncthreads();
        gld_lds16(Ag + k0,               Al);
        gld_lds16(Ag + k0 + 8 * EMB,     Al + 8 * 64);
        gld_lds16(Ag + k0 + 16 * EMB,    Al + 16 * 64);
        gld_lds16(Ag + k0 + 24 * EMB,    Al + 24 * 64);
        gld_lds16(Bg + k0,               Bl);
        gld_lds16(Bg + k0 + 8 * EMB,     Bl + 8 * 64);
        gld_lds16(Bg + k0 + 16 * EMB,    Bl + 16 * 64);
        gld_lds16(Bg + k0 + 24 * EMB,    Bl + 24 * 64);
        __syncthreads();
#pragma unroll
        for (int dk2 = 0; dk2 < 2; ++dk2) {
            bf16x8 af[4], bfr[4];
#pragma unroll
            for (int mi = 0; mi < 4; ++mi)
                af[mi] = ld_frag(&As[(64 * wy + 16 * mi + fm) * 64
                                     + ((dk2 * 32 + fk) ^ key)]);
#pragma unroll
            for (int ni = 0; ni < 4; ++ni)
                bfr[ni] = ld_frag(&Bs[(64 * wx + 16 * ni + fm) * 64
                                      + ((dk2 * 32 + fk) ^ key)]);
#pragma unroll
            for (int mi = 0; mi < 4; ++mi)
#pragma unroll
                for (int ni = 0; ni < 4; ++ni)
                    acc[mi][ni] = __builtin_amdgcn_mfma_f32_16x16x32_bf16(
                        af[mi], bfr[ni], acc[mi][ni], 0, 0, 0);
        }
    }

    const int q4 = (lane >> 4) * 4;
#pragma unroll
    for (int mi = 0; mi < 4; ++mi)
#pragma unroll
        for (int ni = 0; ni < 4; ++ni) {
            const int n = n0 + 64 * wx + 16 * ni + (lane & 15);
            const float bv = bias[n];
#pragma unroll
            for (int r = 0; r < 4; ++r) {
                const int m = m0 + 64 * wy + 16 * mi + q4 + r;
                Out[(size_t)m * EMB + n] = acc[mi][ni][r] + bv;
            }
        }
}

// ============================================================================
// vsuffix: each block derives its own carry (sum of later chunks' csum,
// descending order = original FP order), then walks its 64 rows.
// ============================================================================
__global__ __launch_bounds__(128) void vsuffix_kernel(
    const u16* __restrict__ V, const float* __restrict__ csum,
    u16* __restrict__ vsuf)
{
    const int chunk = blockIdx.x, bh = blockIdx.y, d = threadIdx.x;
    float run = 0.0f;
    for (int c = 31; c > chunk; --c)
        run += csum[((size_t)bh * 32 + c) * HD + d];
    const size_t base = ((size_t)bh * S_LEN + chunk * 64) * HD + d;
    for (int r = 63; r >= 0; --r) {
        vsuf[base + (size_t)r * HD] = f2bf(run);
        run += bf2f(V[base + (size_t)r * HD]);
    }
}

// ============================================================================
// Pipelined flash attention + full-square min, bf16 MFMA.
// R7-proven: 4 waves / 256t, ping-pong chunk width 64, source-side XOR
// swizzle, XCD-locality remap, setprio(1) around MFMA clusters (+5%, m191).
// ============================================================================
__global__ __launch_bounds__(256) void attn_mfma(
    const u16* __restrict__ Q, const u16* __restrict__ K,
    const u16* __restrict__ Vt,
    u16* __restrict__ pacc0, u16* __restrict__ pacc1,
    float* __restrict__ den_p, float* __restrict__ blockmin)
{
    __shared__ __attribute__((aligned(16))) u16 Ps[128 * 136];
    __shared__ __attribute__((aligned(16))) u16 Cs[2][128 * 64];
    __shared__ float den_l[2][128];
    __shared__ float smn[256];

    const int t = threadIdx.x;
    const int w = t >> 6, lane = t & 63;
    const int wy = w >> 1, wx = w & 1;

    // XCD-locality remap (bijective on [0,512)): dispatch id -> logical id.
    const int d_id = blockIdx.y * 16 + blockIdx.x;
    const int f_log = (d_id & 7) * 64 + (d_id >> 3);
    const int pp = (f_log & 15) >> 1, hpar = f_log & 1;
    const int bh = f_log >> 4;
    const int b = bh >> 4, h = bh & 15;

    const u16* __restrict__ Kg  = K + (size_t)bh * S_LEN * HD;
    const u16* __restrict__ Vtg = Vt + (size_t)bh * HD * S_LEN;
    u16* __restrict__ pacc = hpar ? pacc1 : pacc0;

    const int srow8 = lane >> 3;                       // 0..7
    const int scol  = ((lane & 7) ^ srow8) * 8;        // u16 units
    const int fm = lane & 15, fk = (lane >> 4) * 8;
    const int key = (fm & 7) * 8;                      // read-side XOR (u16)
    const int q4 = (lane >> 4) * 4;

#define STAGE_K(b_, j0_, h_) do { \
        const u16* g_ = &Kg[(size_t)((j0_) + w * 32 + srow8) * HD + (h_) * 64 + scol]; \
        u16* l_ = &Cs[b_][(w * 32) * 64]; \
        gld_lds16(g_,           l_); \
        gld_lds16(g_ + 8 * HD,  l_ + 8 * 64); \
        gld_lds16(g_ + 16 * HD, l_ + 16 * 64); \
        gld_lds16(g_ + 24 * HD, l_ + 24 * 64); } while (0)
#define STAGE_V(b_, j0_, h_) do { \
        const u16* g_ = &Vtg[(size_t)(w * 32 + srow8) * S_LEN + (j0_) + (h_) * 64 + scol]; \
        u16* l_ = &Cs[b_][(w * 32) * 64]; \
        gld_lds16(g_,              l_); \
        gld_lds16(g_ + 8 * S_LEN,  l_ + 8 * 64); \
        gld_lds16(g_ + 16 * S_LEN, l_ + 16 * 64); \
        gld_lds16(g_ + 24 * S_LEN, l_ + 24 * 64); } while (0)

    float mn = 3.0e38f;
    int c = 0;

    STAGE_K(0, hpar * 128, 0);
    __syncthreads();

    for (int pass = 0; pass < 2; ++pass) {
        const int qt = pass ? (15 - pp) : pp;
        const int i0 = qt * 128;
        const u16* __restrict__ Qg = Q + ((size_t)bh * S_LEN + i0) * HD;

        bf16x8 af[4][4];
#pragma unroll
        for (int mi = 0; mi < 4; ++mi)
#pragma unroll
            for (int dk = 0; dk < 4; ++dk)
                af[mi][dk] = ld_frag(
                    &Qg[(size_t)(64 * wy + 16 * mi + fm) * HD + dk * 32 + fk]);

        f32x4 oacc[4][4];
#pragma unroll
        for (int i = 0; i < 4; ++i)
#pragma unroll
            for (int j = 0; j < 4; ++j) oacc[i][j] = (f32x4)0.0f;
        float den[4][4] = {};

        for (int ji = 0; ji < 8; ++ji) {
            const int jt = hpar + 2 * ji;
            const int j0 = jt * 128;
            const bool causal = (jt <= qt);
            const bool hn = (ji < 7) || (pass == 0);
            const int nj0 = (ji < 7) ? (jt + 2) * 128 : hpar * 128;

            f32x4 sacc[4][4];
#pragma unroll
            for (int i = 0; i < 4; ++i)
#pragma unroll
                for (int j = 0; j < 4; ++j) sacc[i][j] = (f32x4)0.0f;

            // ---- QK chunk h=0 (d 0..63); prefetch K d-half 1 ----
            STAGE_K(c ^ 1, j0, 1);
#pragma unroll
            for (int dk2 = 0; dk2 < 2; ++dk2) {
                bf16x8 bfr[4];
#pragma unroll
                for (int ni = 0; ni < 4; ++ni)
                    bfr[ni] = ld_frag(&Cs[c][(64 * wx + 16 * ni + fm) * 64
                                             + ((dk2 * 32 + fk) ^ key)]);
                __builtin_amdgcn_s_setprio(1);
#pragma unroll
                for (int mi = 0; mi < 4; ++mi)
#pragma unroll
                    for (int ni = 0; ni < 4; ++ni)
                        sacc[mi][ni] = __builtin_amdgcn_mfma_f32_16x16x32_bf16(
                            af[mi][dk2], bfr[ni], sacc[mi][ni], 0, 0, 0);
                __builtin_amdgcn_s_setprio(0);
            }
            __syncthreads();
            c ^= 1;

            // ---- QK chunk h=1 (d 64..127); prefetch V s-half 0 / next K ----
            if (causal)      STAGE_V(c ^ 1, j0, 0);
            else if (hn)     STAGE_K(c ^ 1, nj0, 0);
#pragma unroll
            for (int dk2 = 0; dk2 < 2; ++dk2) {
                bf16x8 bfr[4];
#pragma unroll
                for (int ni = 0; ni < 4; ++ni)
                    bfr[ni] = ld_frag(&Cs[c][(64 * wx + 16 * ni + fm) * 64
                                             + ((dk2 * 32 + fk) ^ key)]);
                __builtin_amdgcn_s_setprio(1);
#pragma unroll
                for (int mi = 0; mi < 4; ++mi)
#pragma unroll
                    for (int ni = 0; ni < 4; ++ni)
                        sacc[mi][ni] = __builtin_amdgcn_mfma_f32_16x16x32_bf16(
                            af[mi][2 + dk2], bfr[ni], sacc[mi][ni], 0, 0, 0);
                __builtin_amdgcn_s_setprio(0);
            }
            // epilogue overlaps the in-flight DMA
            if (causal) {
                const bool dg = (jt == qt);
#pragma unroll
                for (int mi = 0; mi < 4; ++mi) {
                    const int rbase = 64 * wy + 16 * mi + q4;
#pragma unroll
                    for (int ni = 0; ni < 4; ++ni) {
                        const int cl = 64 * wx + 16 * ni + fm;
                        const int jg = j0 + cl;
#pragma unroll
                        for (int r = 0; r < 4; ++r) {
                            const float s = sacc[mi][ni][r];
                            mn = fminf(mn, s);
                            float e = __expf(s);
                            if (dg && jg > i0 + rbase + r) e = 0.0f;
                            den[mi][r] += e;
                            Ps[(rbase + r) * 136 + cl] = f2bf(e);
                        }
                    }
                }
            } else {
#pragma unroll
                for (int mi = 0; mi < 4; ++mi)
#pragma unroll
                    for (int ni = 0; ni < 4; ++ni)
#pragma unroll
                        for (int r = 0; r < 4; ++r)
                            mn = fminf(mn, sacc[mi][ni][r]);
            }
            __syncthreads();
            c ^= 1;

            // ---- PV: 2 chunks of 64 s-cols (causal only) ----
            if (causal) {
                STAGE_V(c ^ 1, j0, 1);
#pragma unroll
                for (int sk2 = 0; sk2 < 2; ++sk2) {
                    const int sk = sk2;
                    bf16x8 pa[4], pb[4];
#pragma unroll
                    for (int mi = 0; mi < 4; ++mi)
                        pa[mi] = ld_frag(&Ps[(64 * wy + 16 * mi + fm) * 136
                                             + sk * 32 + fk]);
#pragma unroll
                    for (int ni = 0; ni < 4; ++ni)
                        pb[ni] = ld_frag(&Cs[c][(64 * wx + 16 * ni + fm) * 64
                                                + ((sk2 * 32 + fk) ^ key)]);
                    __builtin_amdgcn_s_setprio(1);
#pragma unroll
                    for (int mi = 0; mi < 4; ++mi)
#pragma unroll
                        for (int ni = 0; ni < 4; ++ni)
                            oacc[mi][ni] = __builtin_amdgcn_mfma_f32_16x16x32_bf16(
                                pa[mi], pb[ni], oacc[mi][ni], 0, 0, 0);
                    __builtin_amdgcn_s_setprio(0);
                }
                __syncthreads();
                c ^= 1;

                if (hn) STAGE_K(c ^ 1, nj0, 0);
#pragma unroll
                for (int sk2 = 0; sk2 < 2; ++sk2) {
                    const int sk = 2 + sk2;
                    bf16x8 pa[4], pb[4];
#pragma unroll
                    for (int mi = 0; mi < 4; ++mi)
                        pa[mi] = ld_frag(&Ps[(64 * wy + 16 * mi + fm) * 136
                                             + sk * 32 + fk]);
#pragma unroll
                    for (int ni = 0; ni < 4; ++ni)
                        pb[ni] = ld_frag(&Cs[c][(64 * wx + 16 * ni + fm) * 64
                                                + ((sk2 * 32 + fk) ^ key)]);
                    __builtin_amdgcn_s_setprio(1);
#pragma unroll
                    for (int mi = 0; mi < 4; ++mi)
#pragma unroll
                        for (int ni = 0; ni < 4; ++ni)
                            oacc[mi][ni] = __builtin_amdgcn_mfma_f32_16x16x32_bf16(
                                pa[mi], pb[ni], oacc[mi][ni], 0, 0, 0);
                    __builtin_amdgcn_s_setprio(0);
                }
                __syncthreads();
                c ^= 1;
            }
        }

        // ---- pass epilogue: den reduce + raw partial write ----
#pragma unroll
        for (int mi = 0; mi < 4; ++mi)
#pragma unroll
            for (int r = 0; r < 4; ++r) {
                float v = den[mi][r];
                v += __shfl_xor(v, 1, 64);
                v += __shfl_xor(v, 2, 64);
                v += __shfl_xor(v, 4, 64);
                v += __shfl_xor(v, 8, 64);
                den[mi][r] = v;
            }
        __syncthreads();
        if ((lane & 15) == 0) {
#pragma unroll
            for (int mi = 0; mi < 4; ++mi)
#pragma unroll
                for (int r = 0; r < 4; ++r)
                    den_l[wx][64 * wy + 16 * mi + q4 + r] = den[mi][r];
        }
        __syncthreads();
        if (t < 128)
            den_p[((size_t)hpar * NBH + bh) * S_LEN + i0 + t] =
                den_l[0][t] + den_l[1][t];

#pragma unroll
        for (int mi = 0; mi < 4; ++mi)
#pragma unroll
            for (int ni = 0; ni < 4; ++ni) {
                const int d = 64 * wx + 16 * ni + fm;
#pragma unroll
                for (int r = 0; r < 4; ++r) {
                    const int row = 64 * wy + 16 * mi + q4 + r;
                    pacc[((size_t)b * S_LEN + i0 + row) * EMB + h * HD + d] =
                        f2bf(oacc[mi][ni][r]);
                }
            }
        __syncthreads();  // den_l reuse next pass
    }

    // ---- block min ----
    smn[t] = mn;
    __syncthreads();
    for (int sft = 128; sft > 0; sft >>= 1) {
        if (t < sft) smn[t] = fminf(smn[t], smn[t + sft]);
        __syncthreads();
    }
    if (t == 0) blockmin[d_id] = smn[0];

#undef STAGE_K
#undef STAGE_V
}

// ============================================================================
// finalize: outm = (p0 + p1 + em*vsuf) / (den0 + den1 + (S-1-s)*em), in place.
// Computes the global min from blockmin in-block (deterministic, identical
// reduction order in every block).
// ============================================================================
__global__ __launch_bounds__(256) void finalize_kernel(
    u16* __restrict__ outm, const u16* __restrict__ pacc1,
    const u16* __restrict__ vsuf, const float* __restrict__ den_p,
    const float* __restrict__ blockmin)
{
    __shared__ float wmin[4];
    const int t = threadIdx.x;
    float m = 3.0e38f;
    for (int ii = t; ii < NBMIN; ii += 256)
        m = fminf(m, blockmin[ii]);
    m = fminf(m, __shfl_xor(m, 1, 64));
    m = fminf(m, __shfl_xor(m, 2, 64));
    m = fminf(m, __shfl_xor(m, 4, 64));
    m = fminf(m, __shfl_xor(m, 8, 64));
    m = fminf(m, __shfl_xor(m, 16, 64));
    m = fminf(m, __shfl_xor(m, 32, 64));
    if ((t & 63) == 0) wmin[t >> 6] = m;
    __syncthreads();
    m = fminf(fminf(wmin[0], wmin[1]), fminf(wmin[2], wmin[3]));
    const float em = __expf(m);

    const size_t i = ((size_t)blockIdx.x * 256 + threadIdx.x) * 8;
    const int e = (int)(i & (EMB - 1));
    const int mm = (int)(i / EMB);
    const int b = mm >> 11, s = mm & 2047;
    const int hh = e >> 7, d = e & 127;
    const int bh = b * NH + hh;
    const float den = den_p[(size_t)bh * S_LEN + s]
                    + den_p[((size_t)NBH + bh) * S_LEN + s]
                    + (float)(S_LEN - 1 - s) * em;
    const float inv = 1.0f / den;
    u32x4 a = *(const u32x4*)&outm[i];
    u32x4 cc = *(const u32x4*)&pacc1[i];
    u32x4 vv = *(const u32x4*)&vsuf[((size_t)bh * S_LEN + s) * HD + d];
    const u16* pa = (const u16*)&a;
    const u16* pc = (const u16*)&cc;
    const u16* pv = (const u16*)&vv;
    u16 ov[8];
#pragma unroll
    for (int j = 0; j < 8; ++j) {
        const float v = bf2f(pa[j]) + bf2f(pc[j]) + em * bf2f(pv[j]);
        ov[j] = f2bf(v * inv);
    }
    *(u32x4*)&outm[i] = *(const u32x4*)ov;
}

// ============================================================================
// Launch
// ============================================================================
extern "C" void kernel_launch(void* const* d_in, const int* in_sizes, int n_in,
                              void* d_out, int out_size, void* d_ws, size_t ws_size,
                              hipStream_t stream)
{
    (void)in_sizes; (void)n_in; (void)out_size; (void)ws_size;
    const float* hs = (const float*)d_in[0];
    const float* wq = (const float*)d_in[1];
    const float* wk = (const float*)d_in[2];
    const float* wv = (const float*)d_in[3];
    const float* wo = (const float*)d_in[4];
    const float* bo = (const float*)d_in[5];
    float* out = (float*)d_out;

    char* p = (char*)d_ws;
    const size_t TS = (size_t)NBH * S_LEN * HD;  // 8388608
    u16* Xb   = (u16*)p; p += (size_t)MTOT * EMB * 2;   // dead after gemm_qkv
    u16* Wtq  = (u16*)p; p += (size_t)EMB * EMB * 2;
    u16* Wtk  = (u16*)p; p += (size_t)EMB * EMB * 2;
    u16* Wtv  = (u16*)p; p += (size_t)EMB * EMB * 2;
    u16* Wto  = (u16*)p; p += (size_t)EMB * EMB * 2;
    u16* Qb   = (u16*)p; p += TS * 2;
    u16* Kb   = (u16*)p; p += TS * 2;
    u16* Vb   = (u16*)p; p += TS * 2;
    u16* Vtb  = (u16*)p; p += TS * 2;
    u16* outm = (u16*)p; p += (size_t)MTOT * EMB * 2;   // pacc0, then merged
    u16* vsuf = (u16*)p; p += TS * 2;
    float* csum     = (float*)p; p += (size_t)NBH * 32 * HD * 4;
    float* blockmin = (float*)p; p += 1024 * 4;
    float* den_p    = (float*)p; p += (size_t)2 * NBH * S_LEN * 4;
    u16* pacc1 = Xb;  // overlay: Xb dead once gemm_qkv has run

    prep_kernel<<<dim3(32, 32, 8), 256, 0, stream>>>(
        hs, Xb, wq, wk, wv, wo, Wtq, Wtk, Wtv, Wto);

    gemm_qkv_mfma<<<dim3(EMB / 128, MTOT / 128, 3), 256, 0, stream>>>(
        Xb, Wtq, Wtk, Wtv, Qb, Kb, Vb);

    transpose_v_kernel<<<dim3(32, 2, NBH), 256, 0, stream>>>(Vb, Vtb, csum);
    vsuffix_kernel<<<dim3(32, NBH), 128, 0, stream>>>(Vb, csum, vsuf);

    attn_mfma<<<dim3(16, NBH), 256, 0, stream>>>(
        Qb, Kb, Vtb, outm, pacc1, den_p, blockmin);

    finalize_kernel<<<(MTOT * EMB / 8) / 256, 256, 0, stream>>>(
        outm, pacc1, vsuf, den_p, blockmin);

    gemm_out_mfma<<<dim3(EMB / 128, MTOT / 128), 256, 0, stream>>>(
        outm, Wto, bo, out);
}